// Round 1
// baseline (25420.056 us; speedup 1.0000x reference)
//
#include <hip/hip_runtime.h>
#include <hip/hip_bf16.h>
#include <math.h>

// Problem constants: B=16, N=512, D=256, L=4, H=8, HS=64, FF=1024
// M = B*N = 8192 rows everywhere.

__device__ __forceinline__ float swishf(float x) {
  return x / (1.0f + __expf(-x));
}

// Build dT matrices (row-major dT[i][j] = d[j][i]) for layer 0 (no identity)
// and layers 1..3 (identity-augmented).
__global__ __launch_bounds__(256)
void build_dt(const int* __restrict__ dag, float* __restrict__ dt0, float* __restrict__ dt1)
{
  int idx = blockIdx.x * 256 + threadIdx.x;   // over 512*512
  int i = idx >> 9, j = idx & 511;
  float f = (dag[j * 512 + i] > 0) ? 1.0f : 0.0f;   // clip(dag,0,1) transposed
  dt0[idx] = f;
  dt1[idx] = (i == j) ? 1.0f : f;
}

// Generic fp32 tiled GEMM: C = [resid +] act(A @ B + bias)
// BM=BN=64, BK=16, 256 threads, 4x4 per thread.
// BLAYOUT 0: B row-major (K,N).  BLAYOUT 1: QKV weight (H=8, D=256, HS=64), col n = h*64+c.
// OUTLAYOUT 0: row-major (M,N).  OUTLAYOUT 1: scatter to (B,H,N,HS), row m=b*512+nn, col n=h*64+c.
// Batched over blockIdx.z with strides sB, sC (A shared across batch).
template<int ACT, int BLAYOUT, int OUTLAYOUT, bool RES, bool BIAS>
__global__ __launch_bounds__(256, 2)
void gemm_f32(const float* __restrict__ A, const float* __restrict__ Bm,
              const float* __restrict__ bias, const float* __restrict__ resid,
              float* __restrict__ C, int M, int N, int K,
              long sB, long sC)
{
  constexpr int BM = 64, BN = 64, BK = 16;
  __shared__ float As[BK][BM + 4];   // stride 68 floats (272B, 16B aligned)
  __shared__ float Bs[BK][BN];
  const int bz = blockIdx.z;
  Bm += (long)bz * sB;
  C  += (long)bz * sC;
  const int m0 = blockIdx.y * BM;
  const int n0 = blockIdx.x * BN;
  const int tid = threadIdx.x;
  const int tm = (tid >> 4) << 2;    // 0..60
  const int tn = (tid & 15) << 2;    // 0..60
  const int la_k = tid & 15;
  const int la_m = tid >> 4;
  const int lb_n = tid & 63;
  const int lb_k = tid >> 6;

  float acc[4][4] = {};

  for (int k0 = 0; k0 < K; k0 += BK) {
    #pragma unroll
    for (int r = 0; r < 4; ++r) {
      int m = la_m + r * 16;
      As[la_k][m] = A[(long)(m0 + m) * K + (k0 + la_k)];
    }
    #pragma unroll
    for (int r = 0; r < 4; ++r) {
      int k = lb_k + r * 4;
      int n = n0 + lb_n;
      float v;
      if (BLAYOUT == 0) {
        v = Bm[(long)(k0 + k) * N + n];
      } else {
        int h = n >> 6, c = n & 63;
        v = Bm[((long)h * 256 + (k0 + k)) * 64 + c];
      }
      Bs[k][lb_n] = v;
    }
    __syncthreads();
    #pragma unroll
    for (int kk = 0; kk < BK; ++kk) {
      float4 a4 = *(const float4*)&As[kk][tm];
      float4 b4 = *(const float4*)&Bs[kk][tn];
      float a[4] = {a4.x, a4.y, a4.z, a4.w};
      float b[4] = {b4.x, b4.y, b4.z, b4.w};
      #pragma unroll
      for (int i = 0; i < 4; ++i)
        #pragma unroll
        for (int j = 0; j < 4; ++j)
          acc[i][j] = fmaf(a[i], b[j], acc[i][j]);
    }
    __syncthreads();
  }

  #pragma unroll
  for (int i = 0; i < 4; ++i) {
    long m = m0 + tm + i;
    float v[4];
    #pragma unroll
    for (int j = 0; j < 4; ++j) {
      float x = acc[i][j];
      if (BIAS) x += bias[n0 + tn + j];
      if (ACT == 1) x = swishf(x);
      v[j] = x;
    }
    if (RES) {
      float4 r4 = *(const float4*)&resid[m * N + n0 + tn];
      v[0] += r4.x; v[1] += r4.y; v[2] += r4.z; v[3] += r4.w;
    }
    float4 v4 = make_float4(v[0], v[1], v[2], v[3]);
    if (OUTLAYOUT == 0) {
      *(float4*)&C[m * N + n0 + tn] = v4;
    } else {
      int bb = (int)(m >> 9), nn = (int)(m & 511);
      int n = n0 + tn;
      int h = n >> 6, c = n & 63;
      *(float4*)&C[((long)(bb * 8 + h) << 15) + ((long)nn << 6) + c] = v4;
    }
  }
}

// Two-pass masked attention for one (b,h) and one 64-row i-tile.
// logits = (U @ K^T) / 8 on entries where dT[i][j]==1, else -inf.
// Pass A: per-row max m and sum l (online).  Pass B: A = exp(s-m)/l + 1 (masked),
// O = A @ V  (this equals P@V + dT@V of the reference).
__global__ __launch_bounds__(256, 2)
void attn_f32(const float* __restrict__ Ub, const float* __restrict__ Kb,
              const float* __restrict__ Vb, const float* __restrict__ dtf,
              float* __restrict__ Ob)
{
  __shared__ float Us[64][68];    // U^T: Us[k][i]
  __shared__ float KVs[64][68];   // K^T: [k][j], then V: [j][c]
  __shared__ float Al[64][68];    // A tile [i][j]

  const int bh = blockIdx.y;
  const int b = bh >> 3, h = bh & 7;
  const int i0 = blockIdx.x << 6;
  const float* Up = Ub + (long)bh * 32768;
  const float* Kp = Kb + (long)bh * 32768;
  const float* Vp = Vb + (long)bh * 32768;
  const int tid = threadIdx.x;
  const int tm = (tid >> 4) << 2;
  const int tn = (tid & 15) << 2;
  const int lc = tid & 63;   // load column
  const int lr = tid >> 6;   // load row base (0..3)

  // Load U tile transposed: Us[k][i]
  #pragma unroll
  for (int p = 0; p < 16; ++p) {
    int i = lr + (p << 2);
    Us[lc][i] = Up[(long)(i0 + i) * 64 + lc];
  }

  float m_run[4], l_run[4];
  #pragma unroll
  for (int ii = 0; ii < 4; ++ii) { m_run[ii] = -INFINITY; l_run[ii] = 0.0f; }

  // ---------------- pass A: masked online max & sum ----------------
  for (int jt = 0; jt < 8; ++jt) {
    __syncthreads();
    #pragma unroll
    for (int p = 0; p < 16; ++p) {
      int j = lr + (p << 2);
      KVs[lc][j] = Kp[(long)((jt << 6) + j) * 64 + lc];
    }
    __syncthreads();

    float s[4][4] = {};
    #pragma unroll
    for (int kk = 0; kk < 64; ++kk) {
      float4 a4 = *(const float4*)&Us[kk][tm];
      float4 b4 = *(const float4*)&KVs[kk][tn];
      float a[4] = {a4.x, a4.y, a4.z, a4.w};
      float bb4[4] = {b4.x, b4.y, b4.z, b4.w};
      #pragma unroll
      for (int ii = 0; ii < 4; ++ii)
        #pragma unroll
        for (int jj = 0; jj < 4; ++jj)
          s[ii][jj] = fmaf(a[ii], bb4[jj], s[ii][jj]);
    }

    unsigned mb = 0;
    #pragma unroll
    for (int ii = 0; ii < 4; ++ii) {
      float4 dm = *(const float4*)&dtf[(long)(i0 + tm + ii) * 512 + (jt << 6) + tn];
      if (dm.x != 0.0f) mb |= 1u << (ii * 4 + 0);
      if (dm.y != 0.0f) mb |= 1u << (ii * 4 + 1);
      if (dm.z != 0.0f) mb |= 1u << (ii * 4 + 2);
      if (dm.w != 0.0f) mb |= 1u << (ii * 4 + 3);
    }

    #pragma unroll
    for (int ii = 0; ii < 4; ++ii) {
      float tmax = -INFINITY;
      #pragma unroll
      for (int jj = 0; jj < 4; ++jj)
        if ((mb >> (ii * 4 + jj)) & 1) tmax = fmaxf(tmax, s[ii][jj] * 0.125f);
      #pragma unroll
      for (int off = 1; off < 16; off <<= 1)
        tmax = fmaxf(tmax, __shfl_xor(tmax, off, 64));
      float mnew = fmaxf(m_run[ii], tmax);
      float ts = 0.0f;
      if (mnew > -INFINITY) {
        #pragma unroll
        for (int jj = 0; jj < 4; ++jj)
          if ((mb >> (ii * 4 + jj)) & 1)
            ts += __expf(fmaf(s[ii][jj], 0.125f, -mnew));
      }
      #pragma unroll
      for (int off = 1; off < 16; off <<= 1)
        ts += __shfl_xor(ts, off, 64);
      float scale = (m_run[ii] > -INFINITY) ? __expf(m_run[ii] - mnew) : 0.0f;
      l_run[ii] = fmaf(l_run[ii], scale, ts);
      m_run[ii] = mnew;
    }
  }

  float rl[4];
  #pragma unroll
  for (int ii = 0; ii < 4; ++ii)
    rl[ii] = (l_run[ii] > 0.0f) ? 1.0f / l_run[ii] : 0.0f;

  // ---------------- pass B: O = (exp(s-m)/l + dT) @ V ----------------
  float o[4][4] = {};
  for (int jt = 0; jt < 8; ++jt) {
    __syncthreads();
    #pragma unroll
    for (int p = 0; p < 16; ++p) {
      int j = lr + (p << 2);
      KVs[lc][j] = Kp[(long)((jt << 6) + j) * 64 + lc];
    }
    __syncthreads();

    float s[4][4] = {};
    #pragma unroll
    for (int kk = 0; kk < 64; ++kk) {
      float4 a4 = *(const float4*)&Us[kk][tm];
      float4 b4 = *(const float4*)&KVs[kk][tn];
      float a[4] = {a4.x, a4.y, a4.z, a4.w};
      float bb4[4] = {b4.x, b4.y, b4.z, b4.w};
      #pragma unroll
      for (int ii = 0; ii < 4; ++ii)
        #pragma unroll
        for (int jj = 0; jj < 4; ++jj)
          s[ii][jj] = fmaf(a[ii], bb4[jj], s[ii][jj]);
    }

    unsigned mb = 0;
    #pragma unroll
    for (int ii = 0; ii < 4; ++ii) {
      float4 dm = *(const float4*)&dtf[(long)(i0 + tm + ii) * 512 + (jt << 6) + tn];
      if (dm.x != 0.0f) mb |= 1u << (ii * 4 + 0);
      if (dm.y != 0.0f) mb |= 1u << (ii * 4 + 1);
      if (dm.z != 0.0f) mb |= 1u << (ii * 4 + 2);
      if (dm.w != 0.0f) mb |= 1u << (ii * 4 + 3);
    }

    __syncthreads();   // done reading K from KVs; Al from prev iter consumed

    #pragma unroll
    for (int ii = 0; ii < 4; ++ii)
      #pragma unroll
      for (int jj = 0; jj < 4; ++jj) {
        float av = 0.0f;
        if ((mb >> (ii * 4 + jj)) & 1)
          av = fmaf(__expf(fmaf(s[ii][jj], 0.125f, -m_run[ii])), rl[ii], 1.0f);
        Al[tm + ii][tn + jj] = av;
      }
    #pragma unroll
    for (int p = 0; p < 16; ++p) {
      int j = lr + (p << 2);
      KVs[j][lc] = Vp[(long)((jt << 6) + j) * 64 + lc];
    }
    __syncthreads();

    #pragma unroll
    for (int j4 = 0; j4 < 64; j4 += 4) {
      float4 bv[4];
      #pragma unroll
      for (int r = 0; r < 4; ++r) bv[r] = *(const float4*)&KVs[j4 + r][tn];
      #pragma unroll
      for (int ii = 0; ii < 4; ++ii) {
        float4 av4 = *(const float4*)&Al[tm + ii][j4];
        float a[4] = {av4.x, av4.y, av4.z, av4.w};
        #pragma unroll
        for (int r = 0; r < 4; ++r) {
          o[ii][0] = fmaf(a[r], bv[r].x, o[ii][0]);
          o[ii][1] = fmaf(a[r], bv[r].y, o[ii][1]);
          o[ii][2] = fmaf(a[r], bv[r].z, o[ii][2]);
          o[ii][3] = fmaf(a[r], bv[r].w, o[ii][3]);
        }
      }
    }
  }

  // epilogue: O row-major (8192, 512), row = b*512 + i, col = h*64 + c
  #pragma unroll
  for (int ii = 0; ii < 4; ++ii) {
    long row = (long)b * 512 + i0 + tm + ii;
    float4 v4 = make_float4(o[ii][0], o[ii][1], o[ii][2], o[ii][3]);
    *(float4*)&Ob[row * 512 + h * 64 + tn] = v4;
  }
}

extern "C" void kernel_launch(void* const* d_in, const int* in_sizes, int n_in,
                              void* d_out, int out_size, void* d_ws, size_t ws_size,
                              hipStream_t stream)
{
  const float* X   = (const float*)d_in[0];
  const int*   dag = (const int*)d_in[1];
  const float* Wk  = (const float*)d_in[2];
  const float* bk  = (const float*)d_in[3];
  const float* Wq  = (const float*)d_in[4];
  const float* bq  = (const float*)d_in[5];
  const float* Wv  = (const float*)d_in[6];
  const float* bv  = (const float*)d_in[7];
  const float* Wp  = (const float*)d_in[8];
  const float* bp  = (const float*)d_in[9];
  const float* W1  = (const float*)d_in[10];
  const float* b1  = (const float*)d_in[11];
  const float* W2  = (const float*)d_in[12];
  const float* b2  = (const float*)d_in[13];
  const float* Wlm = (const float*)d_in[14];
  const float* blm = (const float*)d_in[15];
  float* out = (float*)d_out;

  // Workspace layout (floats). Total 23,592,960 floats = ~90 MB.
  // Aliases: Ob = Qb (Q dead after U-GEMM); ff1 = Kb..Vb (K,V dead after attention).
  float* ws  = (float*)d_ws;
  float* dt0 = ws;                    // 262144
  float* dt1 = dt0 + 262144;          // 262144
  float* Qb  = dt1 + 262144;          // 4194304  (also Ob)
  float* Ub  = Qb  + 4194304;         // 4194304
  float* Kb  = Ub  + 4194304;         // 4194304  (ff1 part 1)
  float* Vb  = Kb  + 4194304;         // 4194304  (ff1 part 2)
  float* mha = Vb  + 4194304;         // 2097152
  float* Xa  = mha + 2097152;         // 2097152
  float* Xb  = Xa  + 2097152;         // 2097152
  float* Ob  = Qb;
  float* ff1 = Kb;

  build_dt<<<1024, 256, 0, stream>>>(dag, dt0, dt1);

  const float* Xc = X;
  for (int l = 0; l < 4; ++l) {
    const float* dtf = (l == 0) ? dt0 : dt1;
    // K, Q, V = swish(X @ W + b)  -> (B,H,N,HS)
    gemm_f32<1,1,1,false,true><<<dim3(8,128,1),256,0,stream>>>(
        Xc, Wk + (long)l*131072, bk + l*512, nullptr, Kb, 8192, 512, 256, 0, 0);
    gemm_f32<1,1,1,false,true><<<dim3(8,128,1),256,0,stream>>>(
        Xc, Wq + (long)l*131072, bq + l*512, nullptr, Qb, 8192, 512, 256, 0, 0);
    gemm_f32<1,1,1,false,true><<<dim3(8,128,1),256,0,stream>>>(
        Xc, Wv + (long)l*131072, bv + l*512, nullptr, Vb, 8192, 512, 256, 0, 0);
    // U = dT @ Q   (batched over 128 (b,h), A shared)
    gemm_f32<0,0,0,false,false><<<dim3(1,8,128),256,0,stream>>>(
        dtf, Qb, nullptr, nullptr, Ub, 512, 64, 512, 32768, 32768);
    // attention: O = (softmax_masked((U K^T)/8) + dT) @ V
    attn_f32<<<dim3(8,128,1),256,0,stream>>>(Ub, Kb, Vb, dtf, Ob);
    // mha = swish(O @ Wp + bp)
    gemm_f32<1,0,0,false,true><<<dim3(4,128,1),256,0,stream>>>(
        Ob, Wp + (long)l*131072, bp + l*256, nullptr, mha, 8192, 256, 512, 0, 0);
    // ff1 = swish(mha @ W1 + b1)
    gemm_f32<1,0,0,false,true><<<dim3(16,128,1),256,0,stream>>>(
        mha, W1 + (long)l*262144, b1 + l*1024, nullptr, ff1, 8192, 1024, 256, 0, 0);
    // X_next = mha + ff1 @ W2 + b2
    float* Xn = (l & 1) ? Xb : Xa;
    gemm_f32<0,0,0,true,true><<<dim3(4,128,1),256,0,stream>>>(
        ff1, W2 + (long)l*262144, b2 + l*256, mha, Xn, 8192, 256, 1024, 0, 0);
    Xc = Xn;
  }
  // lm_head: out = X @ Wlm + blm
  gemm_f32<0,0,0,false,true><<<dim3(4,128,1),256,0,stream>>>(
      Xc, Wlm, blm, nullptr, out, 8192, 256, 256, 0, 0);
}

// Round 2
// 2398.948 us; speedup vs baseline: 10.5963x; 10.5963x over previous
//
#include <hip/hip_runtime.h>
#include <hip/hip_bf16.h>
#include <math.h>

// B=16, N=512, D=256, L=4, H=8, HS=64, FF=1024; M = B*N = 8192.
// All GEMMs + attention on MFMA bf16 with hi/lo split (fp32-class accuracy):
//   A@B ~= Ahi@Bhi + Ahi@Blo + Alo@Bhi   (lo*lo dropped, ~2^-17 rel err)
// mfma_f32_16x16x32_bf16 layouts (learn_hip-verified):
//   A-frag: row = lane&15, k = (lane>>4)*8 + e   (8 contiguous k -> 16B load)
//   B-frag: col = lane&15, k = (lane>>4)*8 + e
//   C/D:    col = lane&15, row = (lane>>4)*4 + reg

typedef __attribute__((ext_vector_type(8))) short bf16x8;
typedef __attribute__((ext_vector_type(4))) float f32x4;
typedef unsigned long long u64;

__device__ __forceinline__ short f2bf(float x) {
  unsigned u = __float_as_uint(x);
  unsigned r = (u + 0x7FFFu + ((u >> 16) & 1u)) >> 16;  // RNE
  return (short)r;
}
__device__ __forceinline__ float bf2f(short h) {
  return __uint_as_float(((unsigned)(unsigned short)h) << 16);
}
__device__ __forceinline__ void split_bf(float x, short& hi, short& lo) {
  hi = f2bf(x);
  lo = f2bf(x - bf2f(hi));
}
__device__ __forceinline__ float swishf(float x) { return x / (1.0f + __expf(-x)); }
__device__ __forceinline__ f32x4 mfma16(bf16x8 a, bf16x8 b, f32x4 c) {
  return __builtin_amdgcn_mfma_f32_16x16x32_bf16(a, b, c, 0, 0, 0);
}

// ---------------- weight transpose + split: out(z,C,R) = in(z,R,C) ----------------
__global__ __launch_bounds__(256)
void wsplit(const float* __restrict__ in, short* __restrict__ oh, short* __restrict__ ol,
            int R, int C)
{
  __shared__ float T[64][65];
  const long zin = (long)blockIdx.z * R * C;
  const int r0 = blockIdx.y << 6, c0 = blockIdx.x << 6;
  const int lc = threadIdx.x & 63, p = threadIdx.x >> 6;
#pragma unroll
  for (int q = 0; q < 16; ++q) {
    int rr = p + q * 4;
    T[rr][lc] = in[zin + (long)(r0 + rr) * C + c0 + lc];
  }
  __syncthreads();
#pragma unroll
  for (int q = 0; q < 16; ++q) {
    int cr = p + q * 4;
    float x = T[lc][cr];
    long off = zin + (long)(c0 + cr) * R + r0 + lc;
    short hi, lo; split_bf(x, hi, lo);
    oh[off] = hi; ol[off] = lo;
  }
}

// ---------------- dag -> dT bf16 planes + bitmasks ----------------
__global__ __launch_bounds__(512)
void prep_dt(const int* __restrict__ dag, short* __restrict__ dt0, short* __restrict__ dt1,
             u64* __restrict__ bits0, u64* __restrict__ bits1)
{
  int i = blockIdx.x;        // 512
  int j = threadIdx.x;       // 512
  bool v0 = dag[j * 512 + i] > 0;   // dT[i][j] = clip(dag,0,1)[j][i]
  bool v1 = v0 || (i == j);
  const short one = (short)0x3F80;
  dt0[i * 512 + j] = v0 ? one : (short)0;
  dt1[i * 512 + j] = v1 ? one : (short)0;
  u64 b0 = __ballot(v0), b1 = __ballot(v1);
  if ((j & 63) == 0) { bits0[i * 8 + (j >> 6)] = b0; bits1[i * 8 + (j >> 6)] = b1; }
}

// ---------------- X fp32 -> hi/lo ----------------
__global__ __launch_bounds__(256)
void prep_x(const float* __restrict__ X, short* __restrict__ Xh, short* __restrict__ Xl)
{
  int idx = blockIdx.x * 256 + threadIdx.x;
  short hi, lo; split_bf(X[idx], hi, lo);
  Xh[idx] = hi; Xl[idx] = lo;
}

// ---------------- generic split-bf16 MFMA GEMM ----------------
// C = [resid +] act(A @ B + bias); A (M,K) hi/lo planes; BT (N,K) hi/lo planes.
// OL: 0 row-major (+z*sC), 1 QKV scatter (b,h,n,hs), 2 per-(b,h) transpose (hs,n).
template<int ACT, bool SPLIT_A, bool OF32, bool OHILO, int OL, bool RES, bool BIAS>
__global__ __launch_bounds__(256)
void gemm_mfma(const short* __restrict__ Ah, const short* __restrict__ Al,
               const short* __restrict__ BTh, const short* __restrict__ BTl,
               const float* __restrict__ bias,
               const short* __restrict__ ResH, const short* __restrict__ ResL,
               float* __restrict__ Cf, short* __restrict__ Ch, short* __restrict__ Cl,
               int M, int N, int K, long sB, long sC)
{
  const int z = blockIdx.z;
  BTh += z * sB; BTl += z * sB;
  const int m0 = blockIdx.y << 6, n0 = blockIdx.x << 6;
  const int tid = threadIdx.x, w = tid >> 6, l = tid & 63, g = l >> 4, c = l & 15;
  const long arow = m0 + w * 16 + c;
  const short* aph = Ah + arow * K;
  const short* apl = Al + arow * K;

  f32x4 acc[4] = {};
  for (int k0 = 0; k0 < K; k0 += 32) {
    bf16x8 ah = *(const bf16x8*)(aph + k0 + g * 8);
    bf16x8 al = {};
    if (SPLIT_A) al = *(const bf16x8*)(apl + k0 + g * 8);
#pragma unroll
    for (int ct = 0; ct < 4; ++ct) {
      long boff = (long)(n0 + ct * 16 + c) * K + k0 + g * 8;
      bf16x8 bh = *(const bf16x8*)(BTh + boff);
      bf16x8 bl = *(const bf16x8*)(BTl + boff);
      acc[ct] = mfma16(ah, bh, acc[ct]);
      acc[ct] = mfma16(ah, bl, acc[ct]);
      if (SPLIT_A) acc[ct] = mfma16(al, bh, acc[ct]);
    }
  }

  if constexpr (OL == 2) {
    // transpose epilogue: out plane (b,h): out[hs][n] ; h uniform per block (N=512, BN=64)
    __shared__ float T[64][65];
#pragma unroll
    for (int ct = 0; ct < 4; ++ct) {
      float bv = BIAS ? bias[n0 + ct * 16 + c] : 0.f;
#pragma unroll
      for (int rr = 0; rr < 4; ++rr) {
        float x = acc[ct][rr] + bv;
        if (ACT) x = swishf(x);
        T[w * 16 + g * 4 + rr][ct * 16 + c] = x;
      }
    }
    __syncthreads();
    const int b = m0 >> 9, nn0 = m0 & 511, h = n0 >> 6;
    const long base = ((long)(b * 8 + h)) << 15;  // *32768
    const int hs = tid >> 2, s0 = (tid & 3) << 4;
    short hb[16], lb[16];
#pragma unroll
    for (int e = 0; e < 16; ++e) split_bf(T[s0 + e][hs], hb[e], lb[e]);
    long ob = base + (long)hs * 512 + nn0 + s0;
    *(bf16x8*)(Ch + ob) = *(bf16x8*)&hb[0];
    *(bf16x8*)(Ch + ob + 8) = *(bf16x8*)&hb[8];
    *(bf16x8*)(Cl + ob) = *(bf16x8*)&lb[0];
    *(bf16x8*)(Cl + ob + 8) = *(bf16x8*)&lb[8];
    return;
  }

#pragma unroll
  for (int ct = 0; ct < 4; ++ct) {
    const int col = n0 + ct * 16 + c;
    float bv = BIAS ? bias[col] : 0.f;
#pragma unroll
    for (int rr = 0; rr < 4; ++rr) {
      const long row = m0 + w * 16 + g * 4 + rr;
      float x = acc[ct][rr] + bv;
      if (ACT) x = swishf(x);
      const long roff = row * N + col;
      if (RES) x += bf2f(ResH[roff]) + bf2f(ResL[roff]);
      long off;
      if constexpr (OL == 1) {
        int bb = (int)(row >> 9), nn = (int)(row & 511), h = col >> 6, cc = col & 63;
        off = (((long)(bb * 8 + h) << 9) + nn) * 64 + cc;
      } else {
        off = z * sC + roff;
      }
      if (OF32) Cf[off] = x;
      if (OHILO) { short hi, lo; split_bf(x, hi, lo); Ch[off] = hi; Cl[off] = lo; }
    }
  }
}

// ---------------- fused masked attention (two-pass, MFMA) ----------------
// logits = (U @ K^T)/8 where dT bit set, else -inf; A = exp(s-m)/l + 1 on set bits;
// O = A @ V  (== P@V + dT@V). Dead rows (no bits) -> O row = 0.
#define NEG_INF (-__builtin_inff())

__global__ __launch_bounds__(256)
void attn_mfma(const short* __restrict__ Uh, const short* __restrict__ Ul,
               const short* __restrict__ Kh, const short* __restrict__ Kl,
               const short* __restrict__ VTh, const short* __restrict__ VTl,
               const u64* __restrict__ bits,
               short* __restrict__ Oh, short* __restrict__ Ol)
{
  __shared__ short AsH[4][1024];   // per-wave 16x64 A tile, XOR-swizzled
  __shared__ short AsL[4][1024];
  const int bh = blockIdx.y, b = bh >> 3, h = bh & 7;
  const int i0 = blockIdx.x << 6;
  const int tid = threadIdx.x, w = tid >> 6, l = tid & 63, g = l >> 4, c = l & 15;
  const long plane = (long)bh << 15;
  const short* Uph = Uh + plane;  const short* Upl = Ul + plane;
  const short* Kph = Kh + plane;  const short* Kpl = Kl + plane;
  const short* Vph = VTh + plane; const short* Vpl = VTl + plane;
  const int istrip = i0 + w * 16;
  const float SC = 0.125f;

  bf16x8 ufh[2], ufl[2];
#pragma unroll
  for (int ks = 0; ks < 2; ++ks) {
    long off = (long)(istrip + c) * 64 + ks * 32 + g * 8;
    ufh[ks] = *(const bf16x8*)(Uph + off);
    ufl[ks] = *(const bf16x8*)(Upl + off);
  }

  float m_run[4], l_run[4];
#pragma unroll
  for (int rr = 0; rr < 4; ++rr) { m_run[rr] = NEG_INF; l_run[rr] = 0.f; }

  // ---- pass A: masked online max & sum ----
  for (int jt = 0; jt < 8; ++jt) {
    f32x4 sacc[4] = {};
#pragma unroll
    for (int ct = 0; ct < 4; ++ct)
#pragma unroll
      for (int ks = 0; ks < 2; ++ks) {
        long boff = (long)(jt * 64 + ct * 16 + c) * 64 + ks * 32 + g * 8;
        bf16x8 kfh = *(const bf16x8*)(Kph + boff);
        bf16x8 kfl = *(const bf16x8*)(Kpl + boff);
        sacc[ct] = mfma16(ufh[ks], kfh, sacc[ct]);
        sacc[ct] = mfma16(ufh[ks], kfl, sacc[ct]);
        sacc[ct] = mfma16(ufl[ks], kfh, sacc[ct]);
      }
    u64 wb[4];
#pragma unroll
    for (int rr = 0; rr < 4; ++rr)
      wb[rr] = bits[(long)(istrip + g * 4 + rr) * 8 + jt];
#pragma unroll
    for (int rr = 0; rr < 4; ++rr) {
      float vmax = NEG_INF;
#pragma unroll
      for (int ct = 0; ct < 4; ++ct)
        if ((wb[rr] >> (ct * 16 + c)) & 1ull) vmax = fmaxf(vmax, sacc[ct][rr] * SC);
#pragma unroll
      for (int off = 1; off < 16; off <<= 1)
        vmax = fmaxf(vmax, __shfl_xor(vmax, off, 64));
      float mnew = fmaxf(m_run[rr], vmax);
      float ps = 0.f;
      if (mnew > NEG_INF) {
#pragma unroll
        for (int ct = 0; ct < 4; ++ct)
          if ((wb[rr] >> (ct * 16 + c)) & 1ull)
            ps += __expf(sacc[ct][rr] * SC - mnew);
      }
#pragma unroll
      for (int off = 1; off < 16; off <<= 1)
        ps += __shfl_xor(ps, off, 64);
      float resc = (m_run[rr] > NEG_INF) ? __expf(m_run[rr] - mnew) : 0.f;
      l_run[rr] = l_run[rr] * resc + ps;
      m_run[rr] = mnew;
    }
  }

  float rl[4];
#pragma unroll
  for (int rr = 0; rr < 4; ++rr) rl[rr] = (l_run[rr] > 0.f) ? 1.f / l_run[rr] : 0.f;

  // ---- pass B: O = (exp(s-m)*rl + mask) @ V ----
  f32x4 oacc[4] = {};
  for (int jt = 0; jt < 8; ++jt) {
    f32x4 sacc[4] = {};
#pragma unroll
    for (int ct = 0; ct < 4; ++ct)
#pragma unroll
      for (int ks = 0; ks < 2; ++ks) {
        long boff = (long)(jt * 64 + ct * 16 + c) * 64 + ks * 32 + g * 8;
        bf16x8 kfh = *(const bf16x8*)(Kph + boff);
        bf16x8 kfl = *(const bf16x8*)(Kpl + boff);
        sacc[ct] = mfma16(ufh[ks], kfh, sacc[ct]);
        sacc[ct] = mfma16(ufh[ks], kfl, sacc[ct]);
        sacc[ct] = mfma16(ufl[ks], kfh, sacc[ct]);
      }
    u64 wb[4];
#pragma unroll
    for (int rr = 0; rr < 4; ++rr)
      wb[rr] = bits[(long)(istrip + g * 4 + rr) * 8 + jt];
#pragma unroll
    for (int ct = 0; ct < 4; ++ct)
#pragma unroll
      for (int rr = 0; rr < 4; ++rr) {
        float a = 0.f;
        if ((wb[rr] >> (ct * 16 + c)) & 1ull)
          a = __expf(sacc[ct][rr] * SC - m_run[rr]) * rl[rr] + 1.f;
        short hi, lo; split_bf(a, hi, lo);
        int row = g * 4 + rr;
        int sidx = (row * 64 + ct * 16 + c) ^ ((row & 7) << 3);
        AsH[w][sidx] = hi; AsL[w][sidx] = lo;
      }
#pragma unroll
    for (int ct = 0; ct < 4; ++ct)
#pragma unroll
      for (int js = 0; js < 2; ++js) {
        int k0 = js * 32 + g * 8;
        int ridx = (c * 64 + k0) ^ ((c & 7) << 3);
        bf16x8 afh = *(const bf16x8*)&AsH[w][ridx];
        bf16x8 afl = *(const bf16x8*)&AsL[w][ridx];
        long voff = (long)(ct * 16 + c) * 512 + jt * 64 + k0;
        bf16x8 vfh = *(const bf16x8*)(Vph + voff);
        bf16x8 vfl = *(const bf16x8*)(Vpl + voff);
        oacc[ct] = mfma16(afh, vfh, oacc[ct]);
        oacc[ct] = mfma16(afh, vfl, oacc[ct]);
        oacc[ct] = mfma16(afl, vfh, oacc[ct]);
      }
  }

#pragma unroll
  for (int ct = 0; ct < 4; ++ct)
#pragma unroll
    for (int rr = 0; rr < 4; ++rr) {
      long row = (long)b * 512 + istrip + g * 4 + rr;
      int col = h * 64 + ct * 16 + c;
      short hi, lo; split_bf(oacc[ct][rr], hi, lo);
      Oh[row * 512 + col] = hi; Ol[row * 512 + col] = lo;
    }
}

// ---------------- host ----------------
extern "C" void kernel_launch(void* const* d_in, const int* in_sizes, int n_in,
                              void* d_out, int out_size, void* d_ws, size_t ws_size,
                              hipStream_t stream)
{
  const float* X   = (const float*)d_in[0];
  const int*   dag = (const int*)d_in[1];
  const float* Wk  = (const float*)d_in[2];
  const float* bk  = (const float*)d_in[3];
  const float* Wq  = (const float*)d_in[4];
  const float* bq  = (const float*)d_in[5];
  const float* Wv  = (const float*)d_in[6];
  const float* bv  = (const float*)d_in[7];
  const float* Wp  = (const float*)d_in[8];
  const float* bp  = (const float*)d_in[9];
  const float* W1  = (const float*)d_in[10];
  const float* b1  = (const float*)d_in[11];
  const float* W2  = (const float*)d_in[12];
  const float* b2  = (const float*)d_in[13];
  const float* Wlm = (const float*)d_in[14];
  const float* blm = (const float*)d_in[15];
  float* out = (float*)d_out;

  // ---- workspace layout (~89.3 MB) ----
  char* p = (char*)d_ws;
  auto alloc = [&](size_t bytes) { void* r = p; p += (bytes + 255) & ~(size_t)255; return r; };
  short* WkTh = (short*)alloc(524288 * 2); short* WkTl = (short*)alloc(524288 * 2);
  short* WqTh = (short*)alloc(524288 * 2); short* WqTl = (short*)alloc(524288 * 2);
  short* WvTh = (short*)alloc(524288 * 2); short* WvTl = (short*)alloc(524288 * 2);
  short* WpTh = (short*)alloc(524288 * 2); short* WpTl = (short*)alloc(524288 * 2);
  short* W1Th = (short*)alloc(1048576 * 2); short* W1Tl = (short*)alloc(1048576 * 2);
  short* W2Th = (short*)alloc(1048576 * 2); short* W2Tl = (short*)alloc(1048576 * 2);
  short* WlmTh = (short*)alloc(65536 * 2); short* WlmTl = (short*)alloc(65536 * 2);
  short* dt0b = (short*)alloc(262144 * 2); short* dt1b = (short*)alloc(262144 * 2);
  u64* bits0 = (u64*)alloc(4096 * 8);      u64* bits1 = (u64*)alloc(4096 * 8);
  short* Xh = (short*)alloc(2097152 * 2);  short* Xl = (short*)alloc(2097152 * 2);
  short* KhB = (short*)alloc(4194304 * 2); short* KlB = (short*)alloc(4194304 * 2);   // ff1H spans Kh+Kl
  short* VThB = (short*)alloc(4194304 * 2); short* VTlB = (short*)alloc(4194304 * 2); // ff1L spans VTh+VTl
  short* QThB = (short*)alloc(4194304 * 2); short* QTlB = (short*)alloc(4194304 * 2); // O lives here after U-GEMM
  short* UhB = (short*)alloc(4194304 * 2);  short* UlB = (short*)alloc(4194304 * 2);  // mha lives here after attn
  short* ff1H = KhB;   // 8,388,608 shorts contiguous (Kh+Kl)
  short* ff1L = VThB;  // (VTh+VTl)
  short* OhB = QThB; short* OlB = QTlB;
  short* mhaH = UhB; short* mhaL = UlB;

  // ---- prep (runs every launch; deterministic) ----
  wsplit<<<dim3(1, 4, 32), 256, 0, stream>>>(Wk, WkTh, WkTl, 256, 64);
  wsplit<<<dim3(1, 4, 32), 256, 0, stream>>>(Wq, WqTh, WqTl, 256, 64);
  wsplit<<<dim3(1, 4, 32), 256, 0, stream>>>(Wv, WvTh, WvTl, 256, 64);
  wsplit<<<dim3(4, 8, 4), 256, 0, stream>>>(Wp, WpTh, WpTl, 512, 256);
  wsplit<<<dim3(16, 4, 4), 256, 0, stream>>>(W1, W1Th, W1Tl, 256, 1024);
  wsplit<<<dim3(4, 16, 4), 256, 0, stream>>>(W2, W2Th, W2Tl, 1024, 256);
  wsplit<<<dim3(4, 4, 1), 256, 0, stream>>>(Wlm, WlmTh, WlmTl, 256, 256);
  prep_dt<<<512, 512, 0, stream>>>(dag, dt0b, dt1b, bits0, bits1);
  prep_x<<<8192, 256, 0, stream>>>(X, Xh, Xl);

  for (int ll = 0; ll < 4; ++ll) {
    const short* dtb = ll ? dt1b : dt0b;
    const u64* bts = ll ? bits1 : bits0;
    // K = swish(X@Wk+bk) -> (b,h,n,hs) hi/lo
    gemm_mfma<1, true, false, true, 1, false, true><<<dim3(8, 128, 1), 256, 0, stream>>>(
        Xh, Xl, WkTh + ll * 131072, WkTl + ll * 131072, bk + ll * 512,
        nullptr, nullptr, nullptr, KhB, KlB, 8192, 512, 256, 0, 0);
    // Q -> QT (b,h,hs,n) hi/lo
    gemm_mfma<1, true, false, true, 2, false, true><<<dim3(8, 128, 1), 256, 0, stream>>>(
        Xh, Xl, WqTh + ll * 131072, WqTl + ll * 131072, bq + ll * 512,
        nullptr, nullptr, nullptr, QThB, QTlB, 8192, 512, 256, 0, 0);
    // V -> VT (b,h,hs,n) hi/lo
    gemm_mfma<1, true, false, true, 2, false, true><<<dim3(8, 128, 1), 256, 0, stream>>>(
        Xh, Xl, WvTh + ll * 131072, WvTl + ll * 131072, bv + ll * 512,
        nullptr, nullptr, nullptr, VThB, VTlB, 8192, 512, 256, 0, 0);
    // U = dT @ Q : batched over 128 bh; A = dT bf16 (exact), B = QT
    gemm_mfma<0, false, false, true, 0, false, false><<<dim3(1, 8, 128), 256, 0, stream>>>(
        dtb, dtb, QThB, QTlB, nullptr,
        nullptr, nullptr, nullptr, UhB, UlB, 512, 64, 512, 32768, 32768);
    // attention -> O (8192 x 512) hi/lo (into QT space)
    attn_mfma<<<dim3(8, 128, 1), 256, 0, stream>>>(
        UhB, UlB, KhB, KlB, VThB, VTlB, bts, OhB, OlB);
    // mha = swish(O@Wp+bp) -> hi/lo (into U space)
    gemm_mfma<1, true, false, true, 0, false, true><<<dim3(4, 128, 1), 256, 0, stream>>>(
        OhB, OlB, WpTh + ll * 131072, WpTl + ll * 131072, bp + ll * 256,
        nullptr, nullptr, nullptr, mhaH, mhaL, 8192, 256, 512, 0, 0);
    // ff1 = swish(mha@W1+b1) -> hi/lo (into K+VT space)
    gemm_mfma<1, true, false, true, 0, false, true><<<dim3(16, 128, 1), 256, 0, stream>>>(
        mhaH, mhaL, W1Th + ll * 262144, W1Tl + ll * 262144, b1 + ll * 1024,
        nullptr, nullptr, nullptr, ff1H, ff1L, 8192, 1024, 256, 0, 0);
    // X = mha + ff1@W2 + b2 -> hi/lo (in place)
    gemm_mfma<0, true, false, true, 0, true, true><<<dim3(4, 128, 1), 256, 0, stream>>>(
        ff1H, ff1L, W2Th + ll * 262144, W2Tl + ll * 262144, b2 + ll * 256,
        mhaH, mhaL, nullptr, Xh, Xl, 8192, 256, 1024, 0, 0);
  }
  // lm_head: out = X @ Wlm + blm (fp32)
  gemm_mfma<0, true, true, false, 0, false, true><<<dim3(4, 128, 1), 256, 0, stream>>>(
      Xh, Xl, WlmTh, WlmTl, blm,
      nullptr, nullptr, out, nullptr, nullptr, 8192, 256, 256, 0, 0);
}

// Round 3
// 1249.527 us; speedup vs baseline: 20.3437x; 1.9199x over previous
//
#include <hip/hip_runtime.h>
#include <hip/hip_bf16.h>
#include <math.h>

// B=16, N=512, D=256, L=4, H=8, HS=64, FF=1024; M = B*N = 8192.
// Split-bf16 (Markidis) everywhere: A@B ~= Ah@Bh + Ah@Bl + Al@Bh.
// mfma_f32_16x16x32_bf16: A row=lane&15, k=(lane>>4)*8+e; B col=lane&15, same k;
// D col=lane&15, row=(lane>>4)*4+reg.

typedef __attribute__((ext_vector_type(8))) short bf16x8;
typedef __attribute__((ext_vector_type(4))) float f32x4;
typedef unsigned long long u64;

#define NEG_INF (-__builtin_inff())

__device__ __forceinline__ short f2bf(float x) {
  unsigned u = __float_as_uint(x);
  return (short)((u + 0x7FFFu + ((u >> 16) & 1u)) >> 16);
}
__device__ __forceinline__ float bf2f(short h) {
  return __uint_as_float(((unsigned)(unsigned short)h) << 16);
}
__device__ __forceinline__ void split_bf(float x, short& hi, short& lo) {
  hi = f2bf(x); lo = f2bf(x - bf2f(hi));
}
__device__ __forceinline__ float swishf(float x) { return x / (1.0f + __expf(-x)); }
__device__ __forceinline__ f32x4 mfma16(bf16x8 a, bf16x8 b, f32x4 c) {
  return __builtin_amdgcn_mfma_f32_16x16x32_bf16(a, b, c, 0, 0, 0);
}
__device__ __forceinline__ void gload16(const void* g, void* l) {
  __builtin_amdgcn_global_load_lds(
      (const __attribute__((address_space(1))) void*)g,
      (__attribute__((address_space(3))) void*)l, 16, 0, 0);
}

// ---------------- weight transpose + split ----------------
// out(z): (C,R) = in(z,R,C)^T; out offset = (z/zh)*outLS + (z%zh)*R*C
__global__ __launch_bounds__(256)
void wsplit(const float* __restrict__ in, short* __restrict__ oh, short* __restrict__ ol,
            int R, int C, int zh, long outLS)
{
  __shared__ float T[64][65];
  const int z = blockIdx.z;
  const long zin = (long)z * R * C;
  const long zout = (long)(z / zh) * outLS + (long)(z % zh) * R * C;
  const int r0 = blockIdx.y << 6, c0 = blockIdx.x << 6;
  const int lc = threadIdx.x & 63, p = threadIdx.x >> 6;
#pragma unroll
  for (int q = 0; q < 16; ++q) {
    int rr = p + q * 4;
    T[rr][lc] = in[zin + (long)(r0 + rr) * C + c0 + lc];
  }
  __syncthreads();
#pragma unroll
  for (int q = 0; q < 16; ++q) {
    int cr = p + q * 4;
    float x = T[lc][cr];
    long off = zout + (long)(c0 + cr) * R + r0 + lc;
    short hi, lo; split_bf(x, hi, lo);
    oh[off] = hi; ol[off] = lo;
  }
}

// ---------------- dag -> dT bf16 planes + bitmasks ----------------
__global__ __launch_bounds__(512)
void prep_dt(const int* __restrict__ dag, short* __restrict__ dt0, short* __restrict__ dt1,
             u64* __restrict__ bits0, u64* __restrict__ bits1)
{
  int i = blockIdx.x, j = threadIdx.x;
  bool v0 = dag[j * 512 + i] > 0;
  bool v1 = v0 || (i == j);
  const short one = (short)0x3F80;
  dt0[i * 512 + j] = v0 ? one : (short)0;
  dt1[i * 512 + j] = v1 ? one : (short)0;
  u64 b0 = __ballot(v0), b1 = __ballot(v1);
  if ((j & 63) == 0) { bits0[i * 8 + (j >> 6)] = b0; bits1[i * 8 + (j >> 6)] = b1; }
}

__global__ __launch_bounds__(256)
void prep_x(const float* __restrict__ X, short* __restrict__ Xh, short* __restrict__ Xl)
{
  int idx = blockIdx.x * 256 + threadIdx.x;
  short hi, lo; split_bf(X[idx], hi, lo);
  Xh[idx] = hi; Xl[idx] = lo;
}

__global__ __launch_bounds__(256)
void pack_bias(const float* __restrict__ bk, const float* __restrict__ bq,
               const float* __restrict__ bv, float* __restrict__ bqkv)
{
  int t = blockIdx.x * 256 + threadIdx.x;
  if (t >= 6144) return;
  int l = t / 1536, r = t % 1536;
  float v = (r < 512) ? bk[l * 512 + r] : (r < 1024) ? bq[l * 512 + r - 512] : bv[l * 512 + r - 1024];
  bqkv[t] = v;
}

// ---------------- unified 128-row-tile split-bf16 MFMA GEMM ----------------
// C = [resid +] act(A@B + bias). A (M,K) hi/lo row-major (lda=K). BT (N,K) hi/lo, row
// stride ldb. OMODE 0: row-major hi/lo (ldc, z*sC). 1: f32. 2: transpose ->(b,h,hs,n)
// planes (Q into Ch/Cl, V into Ch2/Cl2), requires BN=128, N<=1024.
template<int BN, int OMODE, bool SPLIT_A, bool ACT, bool BIAS, bool RES>
__global__ __launch_bounds__(256)
void gemm128(const short* __restrict__ Ah, const short* __restrict__ Al,
             const short* __restrict__ BTh, const short* __restrict__ BTl,
             const float* __restrict__ bias,
             const short* __restrict__ ResH, const short* __restrict__ ResL,
             float* __restrict__ Cf, short* __restrict__ Ch, short* __restrict__ Cl,
             int K, int ldb, int ldc, long sB, long sC,
             short* __restrict__ Ch2, short* __restrict__ Cl2)
{
  constexpr int NF = BN / 32;
  constexpr int ASZ = 4 * 128 * 8;            // shorts per A plane
  constexpr int BSZ = 4 * BN * 8;
  constexpr int STG = 2 * ASZ + 2 * BSZ;
  constexpr int SM = (OMODE == 2 && 128 * 136 > STG) ? 128 * 136 : STG;
  __shared__ __align__(16) short smem[SM];
  short* LAh = smem;
  short* LAl = smem + ASZ;
  short* LBh = smem + 2 * ASZ;
  short* LBl = smem + 2 * ASZ + BSZ;

  const int z = blockIdx.z;
  const short* pBh = BTh + (long)z * sB;
  const short* pBl = BTl + (long)z * sB;
  const int n0 = blockIdx.x * BN, m0 = blockIdx.y * 128;
  const int tid = threadIdx.x, lane = tid & 63, w = tid >> 6, g = lane >> 4, c = lane & 15;
  const int wm = w >> 1, wn = w & 1;

  f32x4 acc[4][NF] = {};

  for (int k0 = 0; k0 < K; k0 += 32) {
#pragma unroll
    for (int t = 0; t < 2; ++t) {
      int ss = t * 256 + tid, gi = ss >> 7, row = ss & 127;
      const long go = (long)(m0 + row) * K + k0 + gi * 8;
      gload16(Ah + go, LAh + ss * 8);
      if (SPLIT_A) gload16(Al + go, LAl + ss * 8);
    }
#pragma unroll
    for (int t = 0; t < BN / 64; ++t) {
      int ss = t * 256 + tid, gi = ss / BN, col = ss & (BN - 1);
      const long go = (long)(n0 + col) * ldb + k0 + gi * 8;
      gload16(pBh + go, LBh + ss * 8);
      gload16(pBl + go, LBl + ss * 8);
    }
    __syncthreads();

    bf16x8 a_h[4], a_l[4], b_h[NF], b_l[NF];
#pragma unroll
    for (int i = 0; i < 4; ++i) {
      int idx = (g * 128 + wm * 64 + i * 16 + c) * 8;
      a_h[i] = *(const bf16x8*)(LAh + idx);
      if (SPLIT_A) a_l[i] = *(const bf16x8*)(LAl + idx);
    }
#pragma unroll
    for (int j = 0; j < NF; ++j) {
      int idx = (g * BN + wn * (BN / 2) + j * 16 + c) * 8;
      b_h[j] = *(const bf16x8*)(LBh + idx);
      b_l[j] = *(const bf16x8*)(LBl + idx);
    }
#pragma unroll
    for (int i = 0; i < 4; ++i)
#pragma unroll
      for (int j = 0; j < NF; ++j) {
        acc[i][j] = mfma16(a_h[i], b_h[j], acc[i][j]);
        acc[i][j] = mfma16(a_h[i], b_l[j], acc[i][j]);
        if (SPLIT_A) acc[i][j] = mfma16(a_l[i], b_h[j], acc[i][j]);
      }
    __syncthreads();
  }

  if constexpr (OMODE == 2) {
    short (*T)[136] = reinterpret_cast<short(*)[136]>(smem);
    const int tens = n0 >> 9;              // 0 -> Q planes, 1 -> V planes
    const int h0 = (n0 & 511) >> 6;
    const int b = m0 >> 9, nn0 = m0 & 511;
#pragma unroll
    for (int p = 0; p < 2; ++p) {
      __syncthreads();
#pragma unroll
      for (int j = 0; j < NF; ++j) {
        int cl = wn * 64 + j * 16 + c;
        float bv = BIAS ? bias[n0 + cl] : 0.f;
#pragma unroll
        for (int i = 0; i < 4; ++i)
#pragma unroll
          for (int rr = 0; rr < 4; ++rr) {
            int row = wm * 64 + i * 16 + g * 4 + rr;
            float x = acc[i][j][rr] + bv;
            if (ACT) x = swishf(x);
            short hi = f2bf(x);
            T[cl][row] = p ? f2bf(x - bf2f(hi)) : hi;
          }
      }
      __syncthreads();
      short* dp = p ? (tens ? Cl2 : Cl) : (tens ? Ch2 : Ch);
#pragma unroll
      for (int q = 0; q < 8; ++q) {
        int idx = q * 256 + tid, cl = idx >> 4, r8 = (idx & 15) * 8;
        long ob = ((long)(b * 8 + h0 + (cl >> 6)) << 15) + (long)(cl & 63) * 512 + nn0 + r8;
        *(bf16x8*)(dp + ob) = *(const bf16x8*)&T[cl][r8];
      }
    }
    return;
  }

#pragma unroll
  for (int j = 0; j < NF; ++j) {
    int col = n0 + wn * (BN / 2) + j * 16 + c;
    float bv = BIAS ? bias[col] : 0.f;
#pragma unroll
    for (int i = 0; i < 4; ++i)
#pragma unroll
      for (int rr = 0; rr < 4; ++rr) {
        long row = m0 + wm * 64 + i * 16 + g * 4 + rr;
        float x = acc[i][j][rr] + bv;
        if (ACT) x = swishf(x);
        long off = (long)z * sC + row * ldc + col;
        if (RES) x += bf2f(ResH[off]) + bf2f(ResL[off]);
        if (OMODE == 1) Cf[off] = x;
        else { short hi, lo; split_bf(x, hi, lo); Ch[off] = hi; Cl[off] = lo; }
      }
  }
}

// ---------------- single-pass masked flash attention ----------------
// s = (U@K^T)/8 masked by dT bits; online softmax; O = (exp(s-m)/l)@V + dT@V.
__global__ __launch_bounds__(256)
void attn2(const short* __restrict__ Uh, const short* __restrict__ Ul,
           const short* __restrict__ Kh, const short* __restrict__ Kl,
           const short* __restrict__ VTh, const short* __restrict__ VTl,
           const short* __restrict__ dtb, const u64* __restrict__ bits,
           short* __restrict__ Oh, short* __restrict__ Ol)
{
  __shared__ __align__(16) short LK[2][8][64][8];   // K tile: [plane][hs-grp][j][8]
  __shared__ __align__(16) short LV[2][8][64][8];   // V^T tile: [plane][j-grp][hs][8]
  __shared__ __align__(16) short PA[4][1024];       // per-wave P tile (hi), XOR-swizzled

  const int bh = blockIdx.y, b = bh >> 3, hd = bh & 7;
  const int i0 = blockIdx.x << 6;
  const int tid = threadIdx.x, lane = tid & 63, w = tid >> 6, g = lane >> 4, c = lane & 15;
  const int istrip = i0 + w * 16;
  const long plane = (long)bh << 15;
  const float SC = 0.125f;

  bf16x8 ufh[2], ufl[2];
#pragma unroll
  for (int ks = 0; ks < 2; ++ks) {
    long off = plane + (long)(istrip + c) * 64 + ks * 32 + g * 8;
    ufh[ks] = *(const bf16x8*)(Uh + off);
    ufl[ks] = *(const bf16x8*)(Ul + off);
  }

  float m_run[4], l_run[4];
#pragma unroll
  for (int rr = 0; rr < 4; ++rr) { m_run[rr] = NEG_INF; l_run[rr] = 0.f; }
  f32x4 oe[4] = {}, om[4] = {};

  for (int jt = 0; jt < 8; ++jt) {
#pragma unroll
    for (int t = 0; t < 2; ++t) {
      int ss = t * 256 + tid, gi = ss >> 6, j = ss & 63;
      long ko = (long)(b * 512 + jt * 64 + j) * 512 + hd * 64 + gi * 8;
      gload16(Kh + ko, &LK[0][0][0][0] + ss * 8);
      gload16(Kl + ko, &LK[1][0][0][0] + ss * 8);
      long vo = plane + (long)j * 512 + jt * 64 + gi * 8;   // j here = hs slot
      gload16(VTh + vo, &LV[0][0][0][0] + ss * 8);
      gload16(VTl + vo, &LV[1][0][0][0] + ss * 8);
    }
    __syncthreads();

    // QK^T
    f32x4 sacc[4] = {};
#pragma unroll
    for (int ct = 0; ct < 4; ++ct)
#pragma unroll
      for (int ks = 0; ks < 2; ++ks) {
        bf16x8 kfh = *(const bf16x8*)&LK[0][ks * 4 + g][ct * 16 + c][0];
        bf16x8 kfl = *(const bf16x8*)&LK[1][ks * 4 + g][ct * 16 + c][0];
        sacc[ct] = mfma16(ufh[ks], kfh, sacc[ct]);
        sacc[ct] = mfma16(ufh[ks], kfl, sacc[ct]);
        sacc[ct] = mfma16(ufl[ks], kfh, sacc[ct]);
      }

    u64 wb[4];
#pragma unroll
    for (int rr = 0; rr < 4; ++rr)
      wb[rr] = bits[(long)(istrip + g * 4 + rr) * 8 + jt];

#pragma unroll
    for (int rr = 0; rr < 4; ++rr) {
      float vmax = NEG_INF;
#pragma unroll
      for (int ct = 0; ct < 4; ++ct)
        if ((wb[rr] >> (ct * 16 + c)) & 1ull) vmax = fmaxf(vmax, sacc[ct][rr] * SC);
#pragma unroll
      for (int off = 1; off < 16; off <<= 1)
        vmax = fmaxf(vmax, __shfl_xor(vmax, off, 64));
      float mnew = fmaxf(m_run[rr], vmax);
      float sf = (m_run[rr] > NEG_INF) ? __expf(m_run[rr] - mnew) : 0.f;
      float ps = 0.f, p[4];
#pragma unroll
      for (int ct = 0; ct < 4; ++ct) {
        bool bs = (wb[rr] >> (ct * 16 + c)) & 1ull;
        p[ct] = (bs && mnew > NEG_INF) ? __expf(sacc[ct][rr] * SC - mnew) : 0.f;
        ps += p[ct];
      }
#pragma unroll
      for (int off = 1; off < 16; off <<= 1)
        ps += __shfl_xor(ps, off, 64);
      l_run[rr] = l_run[rr] * sf + ps;
      m_run[rr] = mnew;
#pragma unroll
      for (int ct = 0; ct < 4; ++ct) {
        oe[ct][rr] *= sf;
        int row = g * 4 + rr, jc = ct * 16 + c;
        PA[w][row * 64 + (((jc >> 3) ^ (row & 7)) << 3) + (c & 7)] = f2bf(p[ct]);
      }
    }

    // PV + mask@V
#pragma unroll
    for (int js = 0; js < 2; ++js) {
      int chunk = js * 4 + g;
      bf16x8 pa = *(const bf16x8*)&PA[w][c * 64 + ((chunk ^ (c & 7)) << 3)];
      bf16x8 mf = *(const bf16x8*)(dtb + (long)(istrip + c) * 512 + jt * 64 + js * 32 + g * 8);
#pragma unroll
      for (int ct = 0; ct < 4; ++ct) {
        bf16x8 vfh = *(const bf16x8*)&LV[0][js * 4 + g][ct * 16 + c][0];
        bf16x8 vfl = *(const bf16x8*)&LV[1][js * 4 + g][ct * 16 + c][0];
        oe[ct] = mfma16(pa, vfh, oe[ct]);
        oe[ct] = mfma16(pa, vfl, oe[ct]);
        om[ct] = mfma16(mf, vfh, om[ct]);
        om[ct] = mfma16(mf, vfl, om[ct]);
      }
    }
    __syncthreads();
  }

  float rl[4];
#pragma unroll
  for (int rr = 0; rr < 4; ++rr) rl[rr] = (l_run[rr] > 0.f) ? 1.f / l_run[rr] : 0.f;
#pragma unroll
  for (int ct = 0; ct < 4; ++ct)
#pragma unroll
    for (int rr = 0; rr < 4; ++rr) {
      long row = (long)b * 512 + istrip + g * 4 + rr;
      int col = hd * 64 + ct * 16 + c;
      float x = oe[ct][rr] * rl[rr] + om[ct][rr];
      short hi, lo; split_bf(x, hi, lo);
      Oh[row * 512 + col] = hi; Ol[row * 512 + col] = lo;
    }
}

// ---------------- host ----------------
extern "C" void kernel_launch(void* const* d_in, const int* in_sizes, int n_in,
                              void* d_out, int out_size, void* d_ws, size_t ws_size,
                              hipStream_t stream)
{
  const float* X   = (const float*)d_in[0];
  const int*   dag = (const int*)d_in[1];
  const float* Wk  = (const float*)d_in[2];
  const float* bk  = (const float*)d_in[3];
  const float* Wq  = (const float*)d_in[4];
  const float* bq  = (const float*)d_in[5];
  const float* Wv  = (const float*)d_in[6];
  const float* bv  = (const float*)d_in[7];
  const float* Wp  = (const float*)d_in[8];
  const float* bp  = (const float*)d_in[9];
  const float* W1  = (const float*)d_in[10];
  const float* b1  = (const float*)d_in[11];
  const float* W2  = (const float*)d_in[12];
  const float* b2  = (const float*)d_in[13];
  const float* Wlm = (const float*)d_in[14];
  const float* blm = (const float*)d_in[15];
  float* out = (float*)d_out;

  // ---- workspace (~93.7 MB) ----
  char* p = (char*)d_ws;
  auto alloc = [&](size_t n) { void* r = p; p += (n + 255) & ~(size_t)255; return r; };
  short* WqkvTh = (short*)alloc(1572864 * 2);  // [l][1536][256]: rows K|Q|V
  short* WqkvTl = (short*)alloc(1572864 * 2);
  short* WpTh = (short*)alloc(524288 * 2); short* WpTl = (short*)alloc(524288 * 2);
  short* W1Th = (short*)alloc(1048576 * 2); short* W1Tl = (short*)alloc(1048576 * 2);
  short* W2Th = (short*)alloc(1048576 * 2); short* W2Tl = (short*)alloc(1048576 * 2);
  short* WlmTh = (short*)alloc(65536 * 2); short* WlmTl = (short*)alloc(65536 * 2);
  float* bqkv = (float*)alloc(6144 * 4);
  short* dt0b = (short*)alloc(262144 * 2); short* dt1b = (short*)alloc(262144 * 2);
  u64* bits0 = (u64*)alloc(4096 * 8); u64* bits1 = (u64*)alloc(4096 * 8);
  short* Xh = (short*)alloc(2097152 * 2); short* Xl = (short*)alloc(2097152 * 2);
  short* Kh = (short*)alloc(4194304 * 2); short* Kl = (short*)alloc(4194304 * 2);  // also mha
  short* QTh = (short*)alloc(4194304 * 2); short* QTl = (short*)alloc(4194304 * 2); // also O
  short* VTh = (short*)alloc(4194304 * 2); short* VTl = (short*)alloc(4194304 * 2);
  short* R1h = (short*)alloc(4194304 * 2); short* R1l = (short*)alloc(4194304 * 2); // U / ff1-half
  short* mhaH = Kh, *mhaL = Kl;
  short* Oh = QTh, *Ol = QTl;

  // ---- prep ----
  wsplit<<<dim3(1, 4, 32), 256, 0, stream>>>(Wk, WqkvTh, WqkvTl, 256, 64, 8, 393216);
  wsplit<<<dim3(1, 4, 32), 256, 0, stream>>>(Wq, WqkvTh + 131072, WqkvTl + 131072, 256, 64, 8, 393216);
  wsplit<<<dim3(1, 4, 32), 256, 0, stream>>>(Wv, WqkvTh + 262144, WqkvTl + 262144, 256, 64, 8, 393216);
  wsplit<<<dim3(4, 8, 4), 256, 0, stream>>>(Wp, WpTh, WpTl, 512, 256, 1, 131072);
  wsplit<<<dim3(16, 4, 4), 256, 0, stream>>>(W1, W1Th, W1Tl, 256, 1024, 1, 262144);
  wsplit<<<dim3(4, 16, 4), 256, 0, stream>>>(W2, W2Th, W2Tl, 1024, 256, 1, 262144);
  wsplit<<<dim3(4, 4, 1), 256, 0, stream>>>(Wlm, WlmTh, WlmTl, 256, 256, 1, 65536);
  prep_dt<<<512, 512, 0, stream>>>(dag, dt0b, dt1b, bits0, bits1);
  prep_x<<<8192, 256, 0, stream>>>(X, Xh, Xl);
  pack_bias<<<24, 256, 0, stream>>>(bk, bq, bv, bqkv);

  for (int l = 0; l < 4; ++l) {
    const short* dtb = l ? dt1b : dt0b;
    const u64* bts = l ? bits1 : bits0;
    const long wq = (long)l * 393216;
    // 1. K = swish(X@Wk+bk) -> (8192,512) row-major hi/lo
    gemm128<128, 0, true, true, true, false><<<dim3(4, 64, 1), 256, 0, stream>>>(
        Xh, Xl, WqkvTh + wq, WqkvTl + wq, bqkv + l * 1536, nullptr, nullptr,
        nullptr, Kh, Kl, 256, 256, 512, 0, 0, nullptr, nullptr);
    // 2. Q,V -> transposed planes (b,h,hs,n)
    gemm128<128, 2, true, true, true, false><<<dim3(8, 64, 1), 256, 0, stream>>>(
        Xh, Xl, WqkvTh + wq + 131072, WqkvTl + wq + 131072, bqkv + l * 1536 + 512,
        nullptr, nullptr, nullptr, QTh, QTl, 256, 256, 0, 0, 0, VTh, VTl);
    // 3. U = dT@Q -> (bh,512,64) hi/lo  (A exact, 2 products)
    gemm128<64, 0, false, false, false, false><<<dim3(1, 4, 128), 256, 0, stream>>>(
        dtb, dtb, QTh, QTl, nullptr, nullptr, nullptr,
        nullptr, R1h, R1l, 512, 512, 64, 32768, 32768, nullptr, nullptr);
    // 4. attention -> O (8192,512) hi/lo (into QT space)
    attn2<<<dim3(8, 128, 1), 256, 0, stream>>>(R1h, R1l, Kh, Kl, VTh, VTl, dtb, bts, Oh, Ol);
    // 5. mha = swish(O@Wp+bp) -> (8192,256) (into K space)
    gemm128<64, 0, true, true, true, false><<<dim3(4, 64, 1), 256, 0, stream>>>(
        Oh, Ol, WpTh + l * 131072, WpTl + l * 131072, bp + l * 256, nullptr, nullptr,
        nullptr, mhaH, mhaL, 512, 512, 256, 0, 0, nullptr, nullptr);
    // 6. ff1a = swish(mha@W1[:,:512]+b1a) -> R1
    gemm128<128, 0, true, true, true, false><<<dim3(4, 64, 1), 256, 0, stream>>>(
        mhaH, mhaL, W1Th + l * 262144, W1Tl + l * 262144, b1 + l * 1024, nullptr, nullptr,
        nullptr, R1h, R1l, 256, 256, 512, 0, 0, nullptr, nullptr);
    // 7. X = mha + ff1a@W2[:512,:] + b2
    gemm128<64, 0, true, false, true, true><<<dim3(4, 64, 1), 256, 0, stream>>>(
        R1h, R1l, W2Th + l * 262144, W2Tl + l * 262144, b2 + l * 256, mhaH, mhaL,
        nullptr, Xh, Xl, 512, 1024, 256, 0, 0, nullptr, nullptr);
    // 8. ff1b = swish(mha@W1[:,512:]+b1b) -> R1
    gemm128<128, 0, true, true, true, false><<<dim3(4, 64, 1), 256, 0, stream>>>(
        mhaH, mhaL, W1Th + l * 262144 + 131072, W1Tl + l * 262144 + 131072,
        b1 + l * 1024 + 512, nullptr, nullptr,
        nullptr, R1h, R1l, 256, 256, 512, 0, 0, nullptr, nullptr);
    // 9. X += ff1b@W2[512:,:]
    gemm128<64, 0, true, false, false, true><<<dim3(4, 64, 1), 256, 0, stream>>>(
        R1h, R1l, W2Th + l * 262144 + 512, W2Tl + l * 262144 + 512, nullptr, Xh, Xl,
        nullptr, Xh, Xl, 512, 1024, 256, 0, 0, nullptr, nullptr);
  }
  // lm_head: out = X@Wlm + blm (f32)
  gemm128<64, 1, true, false, true, false><<<dim3(4, 64, 1), 256, 0, stream>>>(
      Xh, Xl, WlmTh, WlmTl, blm, nullptr, nullptr,
      out, nullptr, nullptr, 256, 256, 256, 0, 0, nullptr, nullptr);
}

// Round 4
// 997.156 us; speedup vs baseline: 25.4926x; 1.2531x over previous
//
#include <hip/hip_runtime.h>
#include <hip/hip_bf16.h>
#include <math.h>

// B=16, N=512, D=256, L=4, H=8, HS=64, FF=1024; M = B*N = 8192.
// Split-bf16 (Markidis): A@B ~= Ah@Bh + Ah@Bl + Al@Bh.
// mfma_f32_16x16x32_bf16: A row=lane&15, k=(lane>>4)*8+e; B col=lane&15 same k;
// D col=lane&15, row=(lane>>4)*4+reg.

typedef __attribute__((ext_vector_type(8))) short bf16x8;
typedef __attribute__((ext_vector_type(4))) float f32x4;
typedef unsigned long long u64;

#define NEG_INF (-__builtin_inff())

__device__ __forceinline__ short f2bf(float x) {
  unsigned u = __float_as_uint(x);
  return (short)((u + 0x7FFFu + ((u >> 16) & 1u)) >> 16);
}
__device__ __forceinline__ float bf2f(short h) {
  return __uint_as_float(((unsigned)(unsigned short)h) << 16);
}
__device__ __forceinline__ void split_bf(float x, short& hi, short& lo) {
  hi = f2bf(x); lo = f2bf(x - bf2f(hi));
}
__device__ __forceinline__ float swishf(float x) { return x / (1.0f + __expf(-x)); }
__device__ __forceinline__ f32x4 mfma16(bf16x8 a, bf16x8 b, f32x4 c) {
  return __builtin_amdgcn_mfma_f32_16x16x32_bf16(a, b, c, 0, 0, 0);
}
__device__ __forceinline__ void gload16(const void* g, void* l) {
  __builtin_amdgcn_global_load_lds(
      (const __attribute__((address_space(1))) void*)g,
      (__attribute__((address_space(3))) void*)l, 16, 0, 0);
}

// ---------------- weight transpose + split ----------------
__global__ __launch_bounds__(256)
void wsplit(const float* __restrict__ in, short* __restrict__ oh, short* __restrict__ ol,
            int R, int C, int zh, long outLS)
{
  __shared__ float T[64][65];
  const int z = blockIdx.z;
  const long zin = (long)z * R * C;
  const long zout = (long)(z / zh) * outLS + (long)(z % zh) * R * C;
  const int r0 = blockIdx.y << 6, c0 = blockIdx.x << 6;
  const int lc = threadIdx.x & 63, p = threadIdx.x >> 6;
#pragma unroll
  for (int q = 0; q < 16; ++q) {
    int rr = p + q * 4;
    T[rr][lc] = in[zin + (long)(r0 + rr) * C + c0 + lc];
  }
  __syncthreads();
#pragma unroll
  for (int q = 0; q < 16; ++q) {
    int cr = p + q * 4;
    float x = T[lc][cr];
    long off = zout + (long)(c0 + cr) * R + r0 + lc;
    short hi, lo; split_bf(x, hi, lo);
    oh[off] = hi; ol[off] = lo;
  }
}

// ---------------- dag -> dT bf16 planes + bitmasks ----------------
__global__ __launch_bounds__(512)
void prep_dt(const int* __restrict__ dag, short* __restrict__ dt0, short* __restrict__ dt1,
             u64* __restrict__ bits0, u64* __restrict__ bits1)
{
  int i = blockIdx.x, j = threadIdx.x;
  bool v0 = dag[j * 512 + i] > 0;
  bool v1 = v0 || (i == j);
  const short one = (short)0x3F80;
  dt0[i * 512 + j] = v0 ? one : (short)0;
  dt1[i * 512 + j] = v1 ? one : (short)0;
  u64 b0 = __ballot(v0), b1 = __ballot(v1);
  if ((j & 63) == 0) { bits0[i * 8 + (j >> 6)] = b0; bits1[i * 8 + (j >> 6)] = b1; }
}

__global__ __launch_bounds__(256)
void prep_x(const float* __restrict__ X, short* __restrict__ Xh, short* __restrict__ Xl)
{
  int idx = blockIdx.x * 256 + threadIdx.x;
  short hi, lo; split_bf(X[idx], hi, lo);
  Xh[idx] = hi; Xl[idx] = lo;
}

__global__ __launch_bounds__(256)
void pack_bias(const float* __restrict__ bk, const float* __restrict__ bq,
               const float* __restrict__ bv, float* __restrict__ bqkv)
{
  int t = blockIdx.x * 256 + threadIdx.x;
  if (t >= 6144) return;
  int l = t / 1536, r = t % 1536;
  float v = (r < 512) ? bk[l * 512 + r] : (r < 1024) ? bq[l * 512 + r - 512] : bv[l * 512 + r - 1024];
  bqkv[t] = v;
}

// ---------------- 128-row-tile split-bf16 MFMA GEMM, 2-phase prefetch ----------------
// OMODE 0: row-major hi/lo. 1: f32. 2: fused QKV (n0<512 -> K row-major ldc=512;
//   n0 in [512,1024) -> Q transpose planes Ch2/Cl2; >=1024 -> V planes Ch3/Cl3).
template<int BN, int OMODE, bool SPLIT_A, bool ACT, bool BIAS, bool RES>
__global__ __launch_bounds__(256)
void gemm128(const short* __restrict__ Ah, const short* __restrict__ Al,
             const short* __restrict__ BTh, const short* __restrict__ BTl,
             const float* __restrict__ bias,
             const short* __restrict__ ResH, const short* __restrict__ ResL,
             float* __restrict__ Cf, short* __restrict__ Ch, short* __restrict__ Cl,
             int K, int ldb, int ldc, long sB, long sC,
             short* __restrict__ Ch2, short* __restrict__ Cl2,
             short* __restrict__ Ch3, short* __restrict__ Cl3)
{
  constexpr int NF = BN / 32;
  constexpr int ASZ = 4 * 128 * 8;            // shorts per A plane per buffer
  constexpr int BSZ = 4 * BN * 8;
  constexpr int STG = 2 * ASZ + 2 * BSZ;      // one buffer
  constexpr int SM = (OMODE == 2 && 128 * 136 > 2 * STG) ? 128 * 136 : 2 * STG;
  __shared__ __align__(16) short smem[SM];

  const int z = blockIdx.z;
  const short* pBh = BTh + (long)z * sB;
  const short* pBl = BTl + (long)z * sB;
  const int n0 = blockIdx.x * BN, m0 = blockIdx.y * 128;
  const int tid = threadIdx.x, lane = tid & 63, w = tid >> 6, g = lane >> 4, c = lane & 15;
  const int wm = w >> 1, wn = w & 1;

  auto stage = [&](int bb, int k0) {
    short* LAh = smem + bb * STG;
    short* LAl = LAh + ASZ;
    short* LBh = LAh + 2 * ASZ;
    short* LBl = LBh + BSZ;
#pragma unroll
    for (int t = 0; t < 2; ++t) {
      int ss = t * 256 + tid, gi = ss >> 7, row = ss & 127;
      const long go = (long)(m0 + row) * K + k0 + gi * 8;
      gload16(Ah + go, LAh + ss * 8);
      if (SPLIT_A) gload16(Al + go, LAl + ss * 8);
    }
#pragma unroll
    for (int t = 0; t < BN / 64; ++t) {
      int ss = t * 256 + tid, gi = ss / BN, col = ss & (BN - 1);
      const long go = (long)(n0 + col) * ldb + k0 + gi * 8;
      gload16(pBh + go, LBh + ss * 8);
      gload16(pBl + go, LBl + ss * 8);
    }
  };

  f32x4 acc[4][NF] = {};
  stage(0, 0);
  const int nk = K >> 5;
  for (int ks = 0; ks < nk; ++ks) {
    const int cur = ks & 1;
    __syncthreads();
    if (ks + 1 < nk) stage(cur ^ 1, (ks + 1) << 5);

    short* LAh = smem + cur * STG;
    short* LAl = LAh + ASZ;
    short* LBh = LAh + 2 * ASZ;
    short* LBl = LBh + BSZ;
    bf16x8 a_h[4], a_l[4], b_h[NF], b_l[NF];
#pragma unroll
    for (int i = 0; i < 4; ++i) {
      int idx = (g * 128 + wm * 64 + i * 16 + c) * 8;
      a_h[i] = *(const bf16x8*)(LAh + idx);
      if (SPLIT_A) a_l[i] = *(const bf16x8*)(LAl + idx);
    }
#pragma unroll
    for (int j = 0; j < NF; ++j) {
      int idx = (g * BN + wn * (BN / 2) + j * 16 + c) * 8;
      b_h[j] = *(const bf16x8*)(LBh + idx);
      b_l[j] = *(const bf16x8*)(LBl + idx);
    }
#pragma unroll
    for (int i = 0; i < 4; ++i)
#pragma unroll
      for (int j = 0; j < NF; ++j) {
        acc[i][j] = mfma16(a_h[i], b_h[j], acc[i][j]);
        acc[i][j] = mfma16(a_h[i], b_l[j], acc[i][j]);
        if (SPLIT_A) acc[i][j] = mfma16(a_l[i], b_h[j], acc[i][j]);
      }
  }

  if constexpr (OMODE == 2) {
    const int sel = n0 >> 9;               // 0:K 1:Q 2:V
    if (sel == 0) {
#pragma unroll
      for (int j = 0; j < NF; ++j) {
        int cl = wn * (BN / 2) + j * 16 + c;
        float bv = BIAS ? bias[n0 + cl] : 0.f;
        int col = (n0 & 511) + cl;
#pragma unroll
        for (int i = 0; i < 4; ++i)
#pragma unroll
          for (int rr = 0; rr < 4; ++rr) {
            long row = m0 + wm * 64 + i * 16 + g * 4 + rr;
            float x = acc[i][j][rr] + bv;
            if (ACT) x = swishf(x);
            long off = row * 512 + col;
            short hi, lo; split_bf(x, hi, lo);
            Ch[off] = hi; Cl[off] = lo;
          }
      }
      return;
    }
    short* dph = (sel == 1) ? Ch2 : Ch3;
    short* dpl = (sel == 1) ? Cl2 : Cl3;
    short (*T)[136] = reinterpret_cast<short(*)[136]>(smem);
    const int h0 = (n0 & 511) >> 6;
    const int b = m0 >> 9, nn0 = m0 & 511;
#pragma unroll
    for (int p = 0; p < 2; ++p) {
      __syncthreads();
#pragma unroll
      for (int j = 0; j < NF; ++j) {
        int cl = wn * 64 + j * 16 + c;
        float bv = BIAS ? bias[n0 + cl] : 0.f;
#pragma unroll
        for (int i = 0; i < 4; ++i)
#pragma unroll
          for (int rr = 0; rr < 4; ++rr) {
            int row = wm * 64 + i * 16 + g * 4 + rr;
            float x = acc[i][j][rr] + bv;
            if (ACT) x = swishf(x);
            short hi = f2bf(x);
            T[cl][row] = p ? f2bf(x - bf2f(hi)) : hi;
          }
      }
      __syncthreads();
      short* dp = p ? dpl : dph;
#pragma unroll
      for (int q = 0; q < 8; ++q) {
        int idx = q * 256 + tid, cl = idx >> 4, r8 = (idx & 15) * 8;
        long ob = ((long)(b * 8 + h0 + (cl >> 6)) << 15) + (long)(cl & 63) * 512 + nn0 + r8;
        *(bf16x8*)(dp + ob) = *(const bf16x8*)&T[cl][r8];
      }
    }
    return;
  }

#pragma unroll
  for (int j = 0; j < NF; ++j) {
    int col = n0 + wn * (BN / 2) + j * 16 + c;
    float bv = BIAS ? bias[col] : 0.f;
#pragma unroll
    for (int i = 0; i < 4; ++i)
#pragma unroll
      for (int rr = 0; rr < 4; ++rr) {
        long row = m0 + wm * 64 + i * 16 + g * 4 + rr;
        float x = acc[i][j][rr] + bv;
        if (ACT) x = swishf(x);
        long off = (long)z * sC + row * ldc + col;
        if (RES) x += bf2f(ResH[off]) + bf2f(ResL[off]);
        if (OMODE == 1) Cf[off] = x;
        else { short hi, lo; split_bf(x, hi, lo); Ch[off] = hi; Cl[off] = lo; }
      }
  }
}

// ---------------- single-pass masked flash attention, 2-phase prefetch ----------------
// grid: x = bh (128)  [i-blocks of same bh land on same XCD], y = i-tile (8)
__global__ __launch_bounds__(256)
void attn2(const short* __restrict__ Uh, const short* __restrict__ Ul,
           const short* __restrict__ Kh, const short* __restrict__ Kl,
           const short* __restrict__ VTh, const short* __restrict__ VTl,
           const short* __restrict__ dtb, const u64* __restrict__ bits,
           short* __restrict__ Oh, short* __restrict__ Ol)
{
  __shared__ __align__(16) short LK[2][2][8][64][8];   // [buf][plane][hs-grp][j][8]
  __shared__ __align__(16) short LV[2][2][8][64][8];   // [buf][plane][j-grp][hs][8]
  __shared__ __align__(16) short PA[4][1024];          // per-wave P tile, XOR-swizzled

  const int bh = blockIdx.x, b = bh >> 3, hd = bh & 7;
  const int i0 = blockIdx.y << 6;
  const int tid = threadIdx.x, lane = tid & 63, w = tid >> 6, g = lane >> 4, c = lane & 15;
  const int istrip = i0 + w * 16;
  const long plane = (long)bh << 15;
  const float SC = 0.125f;

  auto stage = [&](int bb, int jt) {
#pragma unroll
    for (int t = 0; t < 2; ++t) {
      int ss = t * 256 + tid, gi = ss >> 6, j = ss & 63;
      long ko = (long)(b * 512 + jt * 64 + j) * 512 + hd * 64 + gi * 8;
      gload16(Kh + ko, &LK[bb][0][0][0][0] + ss * 8);
      gload16(Kl + ko, &LK[bb][1][0][0][0] + ss * 8);
      long vo = plane + (long)j * 512 + jt * 64 + gi * 8;
      gload16(VTh + vo, &LV[bb][0][0][0][0] + ss * 8);
      gload16(VTl + vo, &LV[bb][1][0][0][0] + ss * 8);
    }
  };

  stage(0, 0);

  bf16x8 ufh[2], ufl[2];
#pragma unroll
  for (int ks = 0; ks < 2; ++ks) {
    long off = plane + (long)(istrip + c) * 64 + ks * 32 + g * 8;
    ufh[ks] = *(const bf16x8*)(Uh + off);
    ufl[ks] = *(const bf16x8*)(Ul + off);
  }

  float m_run[4], l_run[4];
#pragma unroll
  for (int rr = 0; rr < 4; ++rr) { m_run[rr] = NEG_INF; l_run[rr] = 0.f; }
  f32x4 oe[4] = {}, om[4] = {};

  for (int jt = 0; jt < 8; ++jt) {
    const int cur = jt & 1;
    __syncthreads();
    if (jt + 1 < 8) stage(cur ^ 1, jt + 1);

    // QK^T
    f32x4 sacc[4] = {};
    __builtin_amdgcn_s_setprio(1);
#pragma unroll
    for (int ct = 0; ct < 4; ++ct)
#pragma unroll
      for (int ks = 0; ks < 2; ++ks) {
        bf16x8 kfh = *(const bf16x8*)&LK[cur][0][ks * 4 + g][ct * 16 + c][0];
        bf16x8 kfl = *(const bf16x8*)&LK[cur][1][ks * 4 + g][ct * 16 + c][0];
        sacc[ct] = mfma16(ufh[ks], kfh, sacc[ct]);
        sacc[ct] = mfma16(ufh[ks], kfl, sacc[ct]);
        sacc[ct] = mfma16(ufl[ks], kfh, sacc[ct]);
      }
    __builtin_amdgcn_s_setprio(0);

    u64 wb[4];
#pragma unroll
    for (int rr = 0; rr < 4; ++rr)
      wb[rr] = bits[(long)(istrip + g * 4 + rr) * 8 + jt];

#pragma unroll
    for (int rr = 0; rr < 4; ++rr) {
      float vmax = NEG_INF;
#pragma unroll
      for (int ct = 0; ct < 4; ++ct)
        if ((wb[rr] >> (ct * 16 + c)) & 1ull) vmax = fmaxf(vmax, sacc[ct][rr] * SC);
#pragma unroll
      for (int off = 1; off < 16; off <<= 1)
        vmax = fmaxf(vmax, __shfl_xor(vmax, off, 64));
      float mnew = fmaxf(m_run[rr], vmax);
      float sf = (m_run[rr] > NEG_INF) ? __expf(m_run[rr] - mnew) : 0.f;
      float ps = 0.f, p[4];
#pragma unroll
      for (int ct = 0; ct < 4; ++ct) {
        bool bs = (wb[rr] >> (ct * 16 + c)) & 1ull;
        p[ct] = (bs && mnew > NEG_INF) ? __expf(sacc[ct][rr] * SC - mnew) : 0.f;
        ps += p[ct];
      }
#pragma unroll
      for (int off = 1; off < 16; off <<= 1)
        ps += __shfl_xor(ps, off, 64);
      l_run[rr] = l_run[rr] * sf + ps;
      m_run[rr] = mnew;
#pragma unroll
      for (int ct = 0; ct < 4; ++ct) {
        oe[ct][rr] *= sf;
        int row = g * 4 + rr, jc = ct * 16 + c;
        PA[w][row * 64 + (((jc >> 3) ^ (row & 7)) << 3) + (c & 7)] = f2bf(p[ct]);
      }
    }

    // PV + mask@V
    __builtin_amdgcn_s_setprio(1);
#pragma unroll
    for (int js = 0; js < 2; ++js) {
      int chunk = js * 4 + g;
      bf16x8 pa = *(const bf16x8*)&PA[w][c * 64 + ((chunk ^ (c & 7)) << 3)];
      bf16x8 mf = *(const bf16x8*)(dtb + (long)(istrip + c) * 512 + jt * 64 + js * 32 + g * 8);
#pragma unroll
      for (int ct = 0; ct < 4; ++ct) {
        bf16x8 vfh = *(const bf16x8*)&LV[cur][0][js * 4 + g][ct * 16 + c][0];
        bf16x8 vfl = *(const bf16x8*)&LV[cur][1][js * 4 + g][ct * 16 + c][0];
        oe[ct] = mfma16(pa, vfh, oe[ct]);
        oe[ct] = mfma16(pa, vfl, oe[ct]);
        om[ct] = mfma16(mf, vfh, om[ct]);
        om[ct] = mfma16(mf, vfl, om[ct]);
      }
    }
    __builtin_amdgcn_s_setprio(0);
  }

  float rl[4];
#pragma unroll
  for (int rr = 0; rr < 4; ++rr) rl[rr] = (l_run[rr] > 0.f) ? 1.f / l_run[rr] : 0.f;
#pragma unroll
  for (int ct = 0; ct < 4; ++ct)
#pragma unroll
    for (int rr = 0; rr < 4; ++rr) {
      long row = (long)b * 512 + istrip + g * 4 + rr;
      int col = hd * 64 + ct * 16 + c;
      float x = oe[ct][rr] * rl[rr] + om[ct][rr];
      short hi, lo; split_bf(x, hi, lo);
      Oh[row * 512 + col] = hi; Ol[row * 512 + col] = lo;
    }
}

// ---------------- host ----------------
extern "C" void kernel_launch(void* const* d_in, const int* in_sizes, int n_in,
                              void* d_out, int out_size, void* d_ws, size_t ws_size,
                              hipStream_t stream)
{
  const float* X   = (const float*)d_in[0];
  const int*   dag = (const int*)d_in[1];
  const float* Wk  = (const float*)d_in[2];
  const float* bk  = (const float*)d_in[3];
  const float* Wq  = (const float*)d_in[4];
  const float* bq  = (const float*)d_in[5];
  const float* Wv  = (const float*)d_in[6];
  const float* bv  = (const float*)d_in[7];
  const float* Wp  = (const float*)d_in[8];
  const float* bp  = (const float*)d_in[9];
  const float* W1  = (const float*)d_in[10];
  const float* b1  = (const float*)d_in[11];
  const float* W2  = (const float*)d_in[12];
  const float* b2  = (const float*)d_in[13];
  const float* Wlm = (const float*)d_in[14];
  const float* blm = (const float*)d_in[15];
  float* out = (float*)d_out;

  // ---- workspace (~93.7 MB), same layout as round 3 ----
  char* p = (char*)d_ws;
  auto alloc = [&](size_t n) { void* r = p; p += (n + 255) & ~(size_t)255; return r; };
  short* WqkvTh = (short*)alloc(1572864 * 2);  // [l][1536][256] rows K|Q|V
  short* WqkvTl = (short*)alloc(1572864 * 2);
  short* WpTh = (short*)alloc(524288 * 2); short* WpTl = (short*)alloc(524288 * 2);
  short* W1Th = (short*)alloc(1048576 * 2); short* W1Tl = (short*)alloc(1048576 * 2);
  short* W2Th = (short*)alloc(1048576 * 2); short* W2Tl = (short*)alloc(1048576 * 2);
  short* WlmTh = (short*)alloc(65536 * 2); short* WlmTl = (short*)alloc(65536 * 2);
  float* bqkv = (float*)alloc(6144 * 4);
  short* dt0b = (short*)alloc(262144 * 2); short* dt1b = (short*)alloc(262144 * 2);
  u64* bits0 = (u64*)alloc(4096 * 8); u64* bits1 = (u64*)alloc(4096 * 8);
  short* Xh = (short*)alloc(2097152 * 2); short* Xl = (short*)alloc(2097152 * 2);
  short* Kh = (short*)alloc(4194304 * 2); short* Kl = (short*)alloc(4194304 * 2);   // also mha
  short* QTh = (short*)alloc(4194304 * 2); short* QTl = (short*)alloc(4194304 * 2); // also O
  short* VTh = (short*)alloc(4194304 * 2); short* VTl = (short*)alloc(4194304 * 2); // ff1H spans VTh+VTl
  short* R1h = (short*)alloc(4194304 * 2); short* R1l = (short*)alloc(4194304 * 2); // U; ff1L spans R1h+R1l
  short* mhaH = Kh, *mhaL = Kl;
  short* Oh = QTh, *Ol = QTl;
  short* ff1H = VTh, *ff1L = R1h;   // each spans two consecutive 4.19M-short allocs

  // ---- prep ----
  wsplit<<<dim3(1, 4, 32), 256, 0, stream>>>(Wk, WqkvTh, WqkvTl, 256, 64, 8, 393216);
  wsplit<<<dim3(1, 4, 32), 256, 0, stream>>>(Wq, WqkvTh + 131072, WqkvTl + 131072, 256, 64, 8, 393216);
  wsplit<<<dim3(1, 4, 32), 256, 0, stream>>>(Wv, WqkvTh + 262144, WqkvTl + 262144, 256, 64, 8, 393216);
  wsplit<<<dim3(4, 8, 4), 256, 0, stream>>>(Wp, WpTh, WpTl, 512, 256, 1, 131072);
  wsplit<<<dim3(16, 4, 4), 256, 0, stream>>>(W1, W1Th, W1Tl, 256, 1024, 1, 262144);
  wsplit<<<dim3(4, 16, 4), 256, 0, stream>>>(W2, W2Th, W2Tl, 1024, 256, 1, 262144);
  wsplit<<<dim3(4, 4, 1), 256, 0, stream>>>(Wlm, WlmTh, WlmTl, 256, 256, 1, 65536);
  prep_dt<<<512, 512, 0, stream>>>(dag, dt0b, dt1b, bits0, bits1);
  prep_x<<<8192, 256, 0, stream>>>(X, Xh, Xl);
  pack_bias<<<24, 256, 0, stream>>>(bk, bq, bv, bqkv);

  for (int l = 0; l < 4; ++l) {
    const short* dtb = l ? dt1b : dt0b;
    const u64* bts = l ? bits1 : bits0;
    const long wq = (long)l * 393216;
    // 1. fused QKV: K row-major; Q,V transposed planes
    gemm128<128, 2, true, true, true, false><<<dim3(12, 64, 1), 256, 0, stream>>>(
        Xh, Xl, WqkvTh + wq, WqkvTl + wq, bqkv + l * 1536, nullptr, nullptr,
        nullptr, Kh, Kl, 256, 256, 512, 0, 0, QTh, QTl, VTh, VTl);
    // 2. U = dT@Q (batched 128 bh)
    gemm128<64, 0, false, false, false, false><<<dim3(1, 4, 128), 256, 0, stream>>>(
        dtb, dtb, QTh, QTl, nullptr, nullptr, nullptr,
        nullptr, R1h, R1l, 512, 512, 64, 32768, 32768, nullptr, nullptr, nullptr, nullptr);
    // 3. attention -> O (into QT space)
    attn2<<<dim3(128, 8, 1), 256, 0, stream>>>(R1h, R1l, Kh, Kl, VTh, VTl, dtb, bts, Oh, Ol);
    // 4. mha = swish(O@Wp+bp) (into K space)
    gemm128<64, 0, true, true, true, false><<<dim3(4, 64, 1), 256, 0, stream>>>(
        Oh, Ol, WpTh + l * 131072, WpTl + l * 131072, bp + l * 256, nullptr, nullptr,
        nullptr, mhaH, mhaL, 512, 512, 256, 0, 0, nullptr, nullptr, nullptr, nullptr);
    // 5. ff1 = swish(mha@W1+b1), full N=1024 (into VT+R1 spans)
    gemm128<128, 0, true, true, true, false><<<dim3(8, 64, 1), 256, 0, stream>>>(
        mhaH, mhaL, W1Th + l * 262144, W1Tl + l * 262144, b1 + l * 1024, nullptr, nullptr,
        nullptr, ff1H, ff1L, 256, 256, 1024, 0, 0, nullptr, nullptr, nullptr, nullptr);
    // 6. X = mha + ff1@W2 + b2
    gemm128<64, 0, true, false, true, true><<<dim3(4, 64, 1), 256, 0, stream>>>(
        ff1H, ff1L, W2Th + l * 262144, W2Tl + l * 262144, b2 + l * 256, mhaH, mhaL,
        nullptr, Xh, Xl, 1024, 1024, 256, 0, 0, nullptr, nullptr, nullptr, nullptr);
  }
  // lm_head: out = X@Wlm + blm (f32)
  gemm128<64, 1, true, false, true, false><<<dim3(4, 64, 1), 256, 0, stream>>>(
      Xh, Xl, WlmTh, WlmTl, blm, nullptr, nullptr,
      out, nullptr, nullptr, 256, 256, 256, 0, 0, nullptr, nullptr, nullptr, nullptr);
}

// Round 5
// 916.420 us; speedup vs baseline: 27.7384x; 1.0881x over previous
//
#include <hip/hip_runtime.h>
#include <hip/hip_bf16.h>
#include <math.h>

// B=16, N=512, D=256, L=4, H=8, HS=64, FF=1024; M = B*N = 8192.
// Mixed-precision scheme (validated by fp32-vs-split absmax identity):
//  - logit path (Q, K, U, QK^T, P): plain bf16 (hi plane only)
//  - magnitude path (V, dT@V, proj, ff1, ff2, X, lm): split-bf16
//    A@B ~= Ah@Bh + Ah@Bl + Al@Bh.
// mfma_f32_16x16x32_bf16: A row=lane&15, k=(lane>>4)*8+e; B col=lane&15 same k;
// D col=lane&15, row=(lane>>4)*4+reg.

typedef __attribute__((ext_vector_type(8))) short bf16x8;
typedef __attribute__((ext_vector_type(4))) float f32x4;
typedef unsigned long long u64;

#define NEG_INF (-__builtin_inff())

__device__ __forceinline__ short f2bf(float x) {
  unsigned u = __float_as_uint(x);
  return (short)((u + 0x7FFFu + ((u >> 16) & 1u)) >> 16);
}
__device__ __forceinline__ float bf2f(short h) {
  return __uint_as_float(((unsigned)(unsigned short)h) << 16);
}
__device__ __forceinline__ void split_bf(float x, short& hi, short& lo) {
  hi = f2bf(x); lo = f2bf(x - bf2f(hi));
}
__device__ __forceinline__ float swishf(float x) { return x / (1.0f + __expf(-x)); }
__device__ __forceinline__ f32x4 mfma16(bf16x8 a, bf16x8 b, f32x4 c) {
  return __builtin_amdgcn_mfma_f32_16x16x32_bf16(a, b, c, 0, 0, 0);
}
__device__ __forceinline__ void gload16(const void* g, void* l) {
  __builtin_amdgcn_global_load_lds(
      (const __attribute__((address_space(1))) void*)g,
      (__attribute__((address_space(3))) void*)l, 16, 0, 0);
}

// ---------------- weight transpose + split (P planes) ----------------
template<int P>
__global__ __launch_bounds__(256)
void wsplit(const float* __restrict__ in, short* __restrict__ oh, short* __restrict__ ol,
            int R, int C, int zh, long outLS)
{
  __shared__ float T[64][65];
  const int z = blockIdx.z;
  const long zin = (long)z * R * C;
  const long zout = (long)(z / zh) * outLS + (long)(z % zh) * R * C;
  const int r0 = blockIdx.y << 6, c0 = blockIdx.x << 6;
  const int lc = threadIdx.x & 63, p = threadIdx.x >> 6;
#pragma unroll
  for (int q = 0; q < 16; ++q) {
    int rr = p + q * 4;
    T[rr][lc] = in[zin + (long)(r0 + rr) * C + c0 + lc];
  }
  __syncthreads();
#pragma unroll
  for (int q = 0; q < 16; ++q) {
    int cr = p + q * 4;
    float x = T[lc][cr];
    long off = zout + (long)(c0 + cr) * R + r0 + lc;
    short hi = f2bf(x);
    oh[off] = hi;
    if (P == 2) ol[off] = f2bf(x - bf2f(hi));
  }
}

// ---------------- dag -> dT bf16 (hi) + bitmasks ----------------
__global__ __launch_bounds__(512)
void prep_dt(const int* __restrict__ dag, short* __restrict__ dt0, short* __restrict__ dt1,
             u64* __restrict__ bits0, u64* __restrict__ bits1)
{
  int i = blockIdx.x, j = threadIdx.x;
  bool v0 = dag[j * 512 + i] > 0;
  bool v1 = v0 || (i == j);
  const short one = (short)0x3F80;
  dt0[i * 512 + j] = v0 ? one : (short)0;
  dt1[i * 512 + j] = v1 ? one : (short)0;
  u64 b0 = __ballot(v0), b1 = __ballot(v1);
  if ((j & 63) == 0) { bits0[i * 8 + (j >> 6)] = b0; bits1[i * 8 + (j >> 6)] = b1; }
}

__global__ __launch_bounds__(256)
void prep_x(const float* __restrict__ X, short* __restrict__ Xh, short* __restrict__ Xl)
{
  int idx = blockIdx.x * 256 + threadIdx.x;
  short hi, lo; split_bf(X[idx], hi, lo);
  Xh[idx] = hi; Xl[idx] = lo;
}

__global__ __launch_bounds__(256)
void pack_kq(const float* __restrict__ bk, const float* __restrict__ bq,
             float* __restrict__ bkq)
{
  int t = blockIdx.x * 256 + threadIdx.x;
  if (t >= 4096) return;
  int l = t >> 10, r = t & 1023;
  bkq[t] = (r < 512) ? bk[l * 512 + r] : bq[l * 512 + r - 512];
}

// ---------------- unified MFMA GEMM, 2-phase prefetch ----------------
// A (M,K): AP planes. BT (N,K): BP planes, row stride ldb, z-batch stride sB.
// mfma/frag = 1 + (BP>1) + (AP>1).
// OM 0: row-major, OP planes (Ch/Cl), ldc, z*sC.
// OM 1: f32 out (Cf).
// OM 2: transpose-scatter to (b,h,hs,n) planes (Ch/Cl), OP planes; h = (n0&511)>>6.
// OM 3: KQ fused: n0<512 -> row-major hi into Ch (ldc=512); else Q^T plane hi into Ch2.
template<int BM, int BN, int AP, int BP, int OM, int OP, bool ACT, bool BIAS, bool RES>
__global__ __launch_bounds__(256)
void gemm(const short* __restrict__ Ah, const short* __restrict__ Al,
          const short* __restrict__ BTh, const short* __restrict__ BTl,
          const float* __restrict__ bias,
          const short* __restrict__ ResH, const short* __restrict__ ResL,
          float* __restrict__ Cf, short* __restrict__ Ch, short* __restrict__ Cl,
          short* __restrict__ Ch2,
          int K, int ldb, int ldc, long sB, long sC)
{
  constexpr int MR = BM / 32, NR = BN / 32;
  constexpr int ABUF = BM * 32;   // shorts per A plane
  constexpr int BBUF = BN * 32;
  constexpr int STG = AP * ABUF + BP * BBUF;
  constexpr int TSZ = (OM >= 2) ? BN * (BM + 8) : 0;
  constexpr int SM = (2 * STG > TSZ) ? 2 * STG : TSZ;
  __shared__ __align__(16) short smem[SM];

  const int z = blockIdx.z;
  const short* pBh = BTh + (long)z * sB;
  const short* pBl = BTl + (long)z * sB;
  const int n0 = blockIdx.x * BN, m0 = blockIdx.y * BM;
  const int tid = threadIdx.x, lane = tid & 63, w = tid >> 6, g = lane >> 4, c = lane & 15;
  const int wm = w >> 1, wn = w & 1;

  auto stage = [&](int bb, int k0) {
    short* LA = smem + bb * STG;
    short* LB = LA + AP * ABUF;
#pragma unroll
    for (int p = 0; p < AP; ++p) {
      const short* src = p ? Al : Ah;
#pragma unroll
      for (int t = 0; t < BM / 64; ++t) {
        int u = t * 256 + tid, gi = u / BM, row = u % BM;
        gload16(src + (long)(m0 + row) * K + k0 + gi * 8, LA + p * ABUF + u * 8);
      }
    }
#pragma unroll
    for (int p = 0; p < BP; ++p) {
      const short* src = p ? pBl : pBh;
#pragma unroll
      for (int t = 0; t < BN / 64; ++t) {
        int u = t * 256 + tid, gi = u / BN, col = u % BN;
        gload16(src + (long)(n0 + col) * ldb + k0 + gi * 8, LB + p * BBUF + u * 8);
      }
    }
  };

  f32x4 acc[MR][NR] = {};
  stage(0, 0);
  const int nk = K >> 5;
  for (int ks = 0; ks < nk; ++ks) {
    const int cur = ks & 1;
    __syncthreads();
    if (ks + 1 < nk) stage(cur ^ 1, (ks + 1) << 5);

    short* LA = smem + cur * STG;
    short* LB = LA + AP * ABUF;
    bf16x8 a_h[MR], a_l[MR], b_h[NR], b_l[NR];
#pragma unroll
    for (int i = 0; i < MR; ++i) {
      int idx = (g * BM + wm * (BM / 2) + i * 16 + c) * 8;
      a_h[i] = *(const bf16x8*)(LA + idx);
      if (AP == 2) a_l[i] = *(const bf16x8*)(LA + ABUF + idx);
    }
#pragma unroll
    for (int j = 0; j < NR; ++j) {
      int idx = (g * BN + wn * (BN / 2) + j * 16 + c) * 8;
      b_h[j] = *(const bf16x8*)(LB + idx);
      if (BP == 2) b_l[j] = *(const bf16x8*)(LB + BBUF + idx);
    }
    __builtin_amdgcn_s_setprio(1);
#pragma unroll
    for (int i = 0; i < MR; ++i)
#pragma unroll
      for (int j = 0; j < NR; ++j) {
        acc[i][j] = mfma16(a_h[i], b_h[j], acc[i][j]);
        if (BP == 2) acc[i][j] = mfma16(a_h[i], b_l[j], acc[i][j]);
        if (AP == 2) acc[i][j] = mfma16(a_l[i], b_h[j], acc[i][j]);
      }
    __builtin_amdgcn_s_setprio(0);
  }

  const bool kq_rowmajor = (OM == 3) && (n0 < 512);
  if (OM == 0 || OM == 1 || kq_rowmajor) {
#pragma unroll
    for (int j = 0; j < NR; ++j) {
      int cl = wn * (BN / 2) + j * 16 + c;
      float bv = BIAS ? bias[n0 + cl] : 0.f;
      int col = (OM == 3) ? ((n0 & 511) + cl) : (n0 + cl);
#pragma unroll
      for (int i = 0; i < MR; ++i)
#pragma unroll
        for (int rr = 0; rr < 4; ++rr) {
          long row = m0 + wm * (BM / 2) + i * 16 + g * 4 + rr;
          float x = acc[i][j][rr] + bv;
          if (ACT) x = swishf(x);
          long off = (long)z * sC + row * ldc + col;
          if (RES) x += bf2f(ResH[off]) + bf2f(ResL[off]);
          if (OM == 1) { Cf[off] = x; }
          else {
            short hi, lo; split_bf(x, hi, lo);
            Ch[off] = hi;
            if (OM == 0 && OP == 2) Cl[off] = lo;
          }
        }
    }
    return;
  }

  if constexpr (OM >= 2) {
    // transpose-scatter epilogue -> (b,h,hs,n) planes
    short (*T)[BM + 8] = reinterpret_cast<short(*)[BM + 8]>(smem);
    const int h0 = (n0 & 511) >> 6;
    const int b = m0 >> 9, nn0 = m0 & 511;
    constexpr int NP = (OM == 3) ? 1 : OP;
#pragma unroll
    for (int p = 0; p < NP; ++p) {
      __syncthreads();
#pragma unroll
      for (int j = 0; j < NR; ++j) {
        int cl = wn * (BN / 2) + j * 16 + c;
        float bv = BIAS ? bias[n0 + cl] : 0.f;
#pragma unroll
        for (int i = 0; i < MR; ++i)
#pragma unroll
          for (int rr = 0; rr < 4; ++rr) {
            int rowl = wm * (BM / 2) + i * 16 + g * 4 + rr;
            float x = acc[i][j][rr] + bv;
            if (ACT) x = swishf(x);
            short hi = f2bf(x);
            T[cl][rowl] = p ? f2bf(x - bf2f(hi)) : hi;
          }
      }
      __syncthreads();
      short* dp = (OM == 3) ? Ch2 : (p ? Cl : Ch);
#pragma unroll
      for (int q = 0; q < BN * BM / 2048; ++q) {
        int idx = q * 256 + tid;
        int cl = idx / (BM / 8), r8 = (idx % (BM / 8)) * 8;
        long ob = ((long)(b * 8 + h0 + (cl >> 6)) << 15) + (long)(cl & 63) * 512 + nn0 + r8;
        *(bf16x8*)(dp + ob) = *(const bf16x8*)&T[cl][r8];
      }
    }
  }
}

// ---------------- masked flash attention (hi-only, PV only) ----------------
// s = (U@K^T)/8 on dT bits else -inf; online softmax; O = (exp(s-m)/l)@V + OI.
// grid: x = bh (XCD locality on K/V), y = i-tile.
__global__ __launch_bounds__(256)
void attn3(const short* __restrict__ Uh, const short* __restrict__ Kh,
           const short* __restrict__ VTh, const u64* __restrict__ bits,
           const float* __restrict__ OIf,
           short* __restrict__ Oh, short* __restrict__ Ol)
{
  __shared__ __align__(16) short LK[2][4096];   // K tile [kgrp][j][8]
  __shared__ __align__(16) short LV[2][4096];   // V^T tile [jgrp][hs][8]
  __shared__ __align__(16) short PA[4][1024];   // per-wave P tile, XOR-swizzled

  const int bh = blockIdx.x, b = bh >> 3, hd = bh & 7;
  const int i0 = blockIdx.y << 6;
  const int tid = threadIdx.x, lane = tid & 63, w = tid >> 6, g = lane >> 4, c = lane & 15;
  const int istrip = i0 + w * 16;
  const long plane = (long)bh << 15;
  const float SC = 0.125f;

  auto stage = [&](int bb, int jt) {
#pragma unroll
    for (int t = 0; t < 2; ++t) {
      int u = t * 256 + tid, gi = u >> 6, j = u & 63;
      long ko = (long)(b * 512 + jt * 64 + j) * 512 + hd * 64 + gi * 8;
      gload16(Kh + ko, &LK[bb][0] + u * 8);
      long vo = plane + (long)j * 512 + jt * 64 + gi * 8;   // j slot = hs row
      gload16(VTh + vo, &LV[bb][0] + u * 8);
    }
  };

  stage(0, 0);

  bf16x8 ufh[2];
#pragma unroll
  for (int ks = 0; ks < 2; ++ks)
    ufh[ks] = *(const bf16x8*)(Uh + plane + (long)(istrip + c) * 64 + ks * 32 + g * 8);

  float m_run[4], l_run[4];
#pragma unroll
  for (int rr = 0; rr < 4; ++rr) { m_run[rr] = NEG_INF; l_run[rr] = 0.f; }
  f32x4 oe[4] = {};

  for (int jt = 0; jt < 8; ++jt) {
    const int cur = jt & 1;
    __syncthreads();
    if (jt + 1 < 8) stage(cur ^ 1, jt + 1);

    f32x4 sacc[4] = {};
    __builtin_amdgcn_s_setprio(1);
#pragma unroll
    for (int ct = 0; ct < 4; ++ct)
#pragma unroll
      for (int ks = 0; ks < 2; ++ks) {
        bf16x8 kf = *(const bf16x8*)&LK[cur][((ks * 4 + g) * 64 + ct * 16 + c) * 8];
        sacc[ct] = mfma16(ufh[ks], kf, sacc[ct]);
      }
    __builtin_amdgcn_s_setprio(0);

    u64 wb[4];
#pragma unroll
    for (int rr = 0; rr < 4; ++rr)
      wb[rr] = bits[(long)(istrip + g * 4 + rr) * 8 + jt];

#pragma unroll
    for (int rr = 0; rr < 4; ++rr) {
      float vmax = NEG_INF;
#pragma unroll
      for (int ct = 0; ct < 4; ++ct)
        if ((wb[rr] >> (ct * 16 + c)) & 1ull) vmax = fmaxf(vmax, sacc[ct][rr] * SC);
#pragma unroll
      for (int off = 1; off < 16; off <<= 1)
        vmax = fmaxf(vmax, __shfl_xor(vmax, off, 64));
      float mnew = fmaxf(m_run[rr], vmax);
      float sf = (m_run[rr] > NEG_INF) ? __expf(m_run[rr] - mnew) : 0.f;
      float ps = 0.f, p[4];
#pragma unroll
      for (int ct = 0; ct < 4; ++ct) {
        bool bs = (wb[rr] >> (ct * 16 + c)) & 1ull;
        p[ct] = (bs && mnew > NEG_INF) ? __expf(sacc[ct][rr] * SC - mnew) : 0.f;
        ps += p[ct];
      }
#pragma unroll
      for (int off = 1; off < 16; off <<= 1)
        ps += __shfl_xor(ps, off, 64);
      l_run[rr] = l_run[rr] * sf + ps;
      m_run[rr] = mnew;
#pragma unroll
      for (int ct = 0; ct < 4; ++ct) {
        oe[ct][rr] *= sf;
        int row = g * 4 + rr, jc = ct * 16 + c;
        PA[w][row * 64 + (((jc >> 3) ^ (row & 7)) << 3) + (c & 7)] = f2bf(p[ct]);
      }
    }

    __builtin_amdgcn_s_setprio(1);
#pragma unroll
    for (int js = 0; js < 2; ++js) {
      int chunk = js * 4 + g;
      bf16x8 pa = *(const bf16x8*)&PA[w][c * 64 + ((chunk ^ (c & 7)) << 3)];
#pragma unroll
      for (int ct = 0; ct < 4; ++ct) {
        bf16x8 vf = *(const bf16x8*)&LV[cur][((js * 4 + g) * 64 + ct * 16 + c) * 8];
        oe[ct] = mfma16(pa, vf, oe[ct]);
      }
    }
    __builtin_amdgcn_s_setprio(0);
  }

  float rl[4];
#pragma unroll
  for (int rr = 0; rr < 4; ++rr) rl[rr] = (l_run[rr] > 0.f) ? 1.f / l_run[rr] : 0.f;
#pragma unroll
  for (int ct = 0; ct < 4; ++ct)
#pragma unroll
    for (int rr = 0; rr < 4; ++rr) {
      int n = istrip + g * 4 + rr;
      int hs = ct * 16 + c;
      float x = oe[ct][rr] * rl[rr] + OIf[plane + (long)n * 64 + hs];
      long row = (long)b * 512 + n;
      short hi, lo; split_bf(x, hi, lo);
      Oh[row * 512 + hd * 64 + hs] = hi;
      Ol[row * 512 + hd * 64 + hs] = lo;
    }
}

// ---------------- host ----------------
extern "C" void kernel_launch(void* const* d_in, const int* in_sizes, int n_in,
                              void* d_out, int out_size, void* d_ws, size_t ws_size,
                              hipStream_t stream)
{
  const float* X   = (const float*)d_in[0];
  const int*   dag = (const int*)d_in[1];
  const float* Wk  = (const float*)d_in[2];
  const float* bk  = (const float*)d_in[3];
  const float* Wq  = (const float*)d_in[4];
  const float* bq  = (const float*)d_in[5];
  const float* Wv  = (const float*)d_in[6];
  const float* bv  = (const float*)d_in[7];
  const float* Wp  = (const float*)d_in[8];
  const float* bp  = (const float*)d_in[9];
  const float* W1  = (const float*)d_in[10];
  const float* b1  = (const float*)d_in[11];
  const float* W2  = (const float*)d_in[12];
  const float* b2  = (const float*)d_in[13];
  const float* Wlm = (const float*)d_in[14];
  const float* blm = (const float*)d_in[15];
  float* out = (float*)d_out;

  // ---- workspace (~83 MB) ----
  char* p = (char*)d_ws;
  auto alloc = [&](size_t n) { void* r = p; p += (n + 255) & ~(size_t)255; return r; };
  short* WkqTh = (short*)alloc(1048576 * 2);                 // [l][1024][256] hi (K|Q)
  short* WvTh = (short*)alloc(524288 * 2); short* WvTl = (short*)alloc(524288 * 2);
  short* WpTh = (short*)alloc(524288 * 2); short* WpTl = (short*)alloc(524288 * 2);
  short* W1Th = (short*)alloc(1048576 * 2); short* W1Tl = (short*)alloc(1048576 * 2);
  short* W2Th = (short*)alloc(1048576 * 2); short* W2Tl = (short*)alloc(1048576 * 2);
  short* WlmTh = (short*)alloc(65536 * 2); short* WlmTl = (short*)alloc(65536 * 2);
  float* bkq = (float*)alloc(4096 * 4);
  short* dt0b = (short*)alloc(262144 * 2); short* dt1b = (short*)alloc(262144 * 2);
  u64* bits0 = (u64*)alloc(4096 * 8); u64* bits1 = (u64*)alloc(4096 * 8);
  short* Xh = (short*)alloc(2097152 * 2); short* Xl = (short*)alloc(2097152 * 2);
  short* Kh = (short*)alloc(4194304 * 2);                    // also mha hi+lo (2M+2M)
  short* QTh = (short*)alloc(4194304 * 2);                   // also O hi
  short* VTh = (short*)alloc(4194304 * 2); short* VTl = (short*)alloc(4194304 * 2); // ff1 hi span
  short* Uh  = (short*)alloc(4194304 * 2);                   // ff1 lo span (w/ OIf)
  float* OIf = (float*)alloc(4194304 * 4);
  short* Olo = (short*)alloc(4194304 * 2);                   // O lo
  short* mhaH = Kh, *mhaL = Kh + 2097152;
  short* Oh = QTh;
  short* ff1H = VTh;            // spans VTh+VTl  (8,388,608 shorts)
  short* ff1L = Uh;             // spans Uh + first half of OIf

  // ---- prep ----
  wsplit<1><<<dim3(1, 4, 32), 256, 0, stream>>>(Wk, WkqTh, nullptr, 256, 64, 8, 262144);
  wsplit<1><<<dim3(1, 4, 32), 256, 0, stream>>>(Wq, WkqTh + 131072, nullptr, 256, 64, 8, 262144);
  wsplit<2><<<dim3(1, 4, 32), 256, 0, stream>>>(Wv, WvTh, WvTl, 256, 64, 8, 131072);
  wsplit<2><<<dim3(4, 8, 4), 256, 0, stream>>>(Wp, WpTh, WpTl, 512, 256, 1, 131072);
  wsplit<2><<<dim3(16, 4, 4), 256, 0, stream>>>(W1, W1Th, W1Tl, 256, 1024, 1, 262144);
  wsplit<2><<<dim3(4, 16, 4), 256, 0, stream>>>(W2, W2Th, W2Tl, 1024, 256, 1, 262144);
  wsplit<2><<<dim3(4, 4, 1), 256, 0, stream>>>(Wlm, WlmTh, WlmTl, 256, 256, 1, 65536);
  prep_dt<<<512, 512, 0, stream>>>(dag, dt0b, dt1b, bits0, bits1);
  prep_x<<<8192, 256, 0, stream>>>(X, Xh, Xl);
  pack_kq<<<16, 256, 0, stream>>>(bk, bq, bkq);

  for (int l = 0; l < 4; ++l) {
    const short* dtb = l ? dt1b : dt0b;
    const u64* bts = l ? bits1 : bits0;
    // 1. KQ fused: K row-major hi (Ch), Q^T plane hi (Ch2)
    gemm<128, 64, 1, 1, 3, 1, true, true, false><<<dim3(16, 64), 256, 0, stream>>>(
        Xh, nullptr, WkqTh + l * 262144, nullptr, bkq + l * 1024, nullptr, nullptr,
        nullptr, Kh, nullptr, QTh, 256, 256, 512, 0, 0);
    // 2. V -> V^T planes hi/lo (full split)
    gemm<128, 64, 2, 2, 2, 2, true, true, false><<<dim3(8, 64), 256, 0, stream>>>(
        Xh, Xl, WvTh + l * 131072, WvTl + l * 131072, bv + l * 512, nullptr, nullptr,
        nullptr, VTh, VTl, nullptr, 256, 256, 0, 0, 0);
    // 3. U = dT@Q (hi-only), batched over bh
    gemm<128, 64, 1, 1, 0, 1, false, false, false><<<dim3(1, 4, 128), 256, 0, stream>>>(
        dtb, nullptr, QTh, nullptr, nullptr, nullptr, nullptr,
        nullptr, Uh, nullptr, nullptr, 512, 512, 64, 32768, 32768);
    // 4. OI = dT@V (split-V), f32 out, batched over bh
    gemm<128, 64, 1, 2, 1, 1, false, false, false><<<dim3(1, 4, 128), 256, 0, stream>>>(
        dtb, nullptr, VTh, VTl, nullptr, nullptr, nullptr,
        OIf, nullptr, nullptr, nullptr, 512, 512, 64, 32768, 32768);
    // 5. attention: O = softmax(U K^T /8, mask)@V + OI
    attn3<<<dim3(128, 8), 256, 0, stream>>>(Uh, Kh, VTh, bts, OIf, Oh, Olo);
    // 6. mha = swish(O@Wp+bp)
    gemm<64, 64, 2, 2, 0, 2, true, true, false><<<dim3(4, 128), 256, 0, stream>>>(
        Oh, Olo, WpTh + l * 131072, WpTl + l * 131072, bp + l * 256, nullptr, nullptr,
        nullptr, mhaH, mhaL, nullptr, 512, 512, 256, 0, 0);
    // 7. ff1 = swish(mha@W1+b1)
    gemm<128, 64, 2, 2, 0, 2, true, true, false><<<dim3(16, 64), 256, 0, stream>>>(
        mhaH, mhaL, W1Th + l * 262144, W1Tl + l * 262144, b1 + l * 1024, nullptr, nullptr,
        nullptr, ff1H, ff1L, nullptr, 256, 256, 1024, 0, 0);
    // 8. X = mha + ff1@W2 + b2
    gemm<64, 64, 2, 2, 0, 2, false, true, true><<<dim3(4, 128), 256, 0, stream>>>(
        ff1H, ff1L, W2Th + l * 262144, W2Tl + l * 262144, b2 + l * 256, mhaH, mhaL,
        nullptr, Xh, Xl, nullptr, 1024, 1024, 256, 0, 0);
  }
  // lm_head: out = X@Wlm + blm (f32)
  gemm<64, 64, 2, 2, 1, 1, false, true, false><<<dim3(4, 128), 256, 0, stream>>>(
      Xh, Xl, WlmTh, WlmTl, blm, nullptr, nullptr,
      out, nullptr, nullptr, nullptr, 256, 256, 256, 0, 0);
}

// Round 6
// 794.579 us; speedup vs baseline: 31.9919x; 1.1533x over previous
//
#include <hip/hip_runtime.h>
#include <hip/hip_bf16.h>
#include <math.h>

// B=16, N=512, D=256, L=4, H=8, HS=64, FF=1024; M = B*N = 8192.
// Precision plan (exponential activation growth => only last-layer error matters):
//  - logit path (K, Q, U, QK^T, P): hi bf16
//  - V / dT@V / proj: hi bf16 (single-layer ~0.2-0.4% rel err, budget 2%)
//  - trunk (ff1, ff2, X, mha, lm): split-bf16  A@B ~= Ah@Bh + Ah@Bl + Al@Bh
// mfma_f32_16x16x32_bf16: A row=lane&15, k=(lane>>4)*8+e; B col=lane&15 same k;
// D col=lane&15, row=(lane>>4)*4+reg.

typedef __attribute__((ext_vector_type(8))) short bf16x8;
typedef __attribute__((ext_vector_type(4))) float f32x4;
typedef unsigned long long u64;

#define NEG_INF (-__builtin_inff())

__device__ __forceinline__ short f2bf(float x) {
  unsigned u = __float_as_uint(x);
  return (short)((u + 0x7FFFu + ((u >> 16) & 1u)) >> 16);
}
__device__ __forceinline__ float bf2f(short h) {
  return __uint_as_float(((unsigned)(unsigned short)h) << 16);
}
__device__ __forceinline__ void split_bf(float x, short& hi, short& lo) {
  hi = f2bf(x); lo = f2bf(x - bf2f(hi));
}
__device__ __forceinline__ float swishf(float x) { return x / (1.0f + __expf(-x)); }
__device__ __forceinline__ f32x4 mfma16(bf16x8 a, bf16x8 b, f32x4 c) {
  return __builtin_amdgcn_mfma_f32_16x16x32_bf16(a, b, c, 0, 0, 0);
}
__device__ __forceinline__ void gload16(const void* g, void* l) {
  __builtin_amdgcn_global_load_lds(
      (const __attribute__((address_space(1))) void*)g,
      (__attribute__((address_space(3))) void*)l, 16, 0, 0);
}
__device__ __forceinline__ unsigned cvtpk(float a, float b) {  // lo=bf16(a), hi=bf16(b)
  unsigned r;
  asm("v_cvt_pk_bf16_f32 %0, %1, %2" : "=v"(r) : "v"(a), "v"(b));
  return r;
}

// ---------------- weight transpose + split (P planes) ----------------
template<int P>
__global__ __launch_bounds__(256)
void wsplit(const float* __restrict__ in, short* __restrict__ oh, short* __restrict__ ol,
            int R, int C, int zh, long outLS)
{
  __shared__ float T[64][65];
  const int z = blockIdx.z;
  const long zin = (long)z * R * C;
  const long zout = (long)(z / zh) * outLS + (long)(z % zh) * R * C;
  const int r0 = blockIdx.y << 6, c0 = blockIdx.x << 6;
  const int lc = threadIdx.x & 63, p = threadIdx.x >> 6;
#pragma unroll
  for (int q = 0; q < 16; ++q) {
    int rr = p + q * 4;
    T[rr][lc] = in[zin + (long)(r0 + rr) * C + c0 + lc];
  }
  __syncthreads();
#pragma unroll
  for (int q = 0; q < 16; ++q) {
    int cr = p + q * 4;
    float x = T[lc][cr];
    long off = zout + (long)(c0 + cr) * R + r0 + lc;
    short hi = f2bf(x);
    oh[off] = hi;
    if (P == 2) ol[off] = f2bf(x - bf2f(hi));
  }
}

// ---------------- dag -> dT bf16 (hi) + bitmasks ----------------
__global__ __launch_bounds__(512)
void prep_dt(const int* __restrict__ dag, short* __restrict__ dt0, short* __restrict__ dt1,
             u64* __restrict__ bits0, u64* __restrict__ bits1)
{
  int i = blockIdx.x, j = threadIdx.x;
  bool v0 = dag[j * 512 + i] > 0;
  bool v1 = v0 || (i == j);
  const short one = (short)0x3F80;
  dt0[i * 512 + j] = v0 ? one : (short)0;
  dt1[i * 512 + j] = v1 ? one : (short)0;
  u64 b0 = __ballot(v0), b1 = __ballot(v1);
  if ((j & 63) == 0) { bits0[i * 8 + (j >> 6)] = b0; bits1[i * 8 + (j >> 6)] = b1; }
}

__global__ __launch_bounds__(256)
void prep_x(const float* __restrict__ X, short* __restrict__ Xh, short* __restrict__ Xl)
{
  int idx = blockIdx.x * 256 + threadIdx.x;
  short hi, lo; split_bf(X[idx], hi, lo);
  Xh[idx] = hi; Xl[idx] = lo;
}

__global__ __launch_bounds__(256)
void pack_kq(const float* __restrict__ bk, const float* __restrict__ bq,
             float* __restrict__ bkq)
{
  int t = blockIdx.x * 256 + threadIdx.x;
  if (t >= 4096) return;
  int l = t >> 10, r = t & 1023;
  bkq[t] = (r < 512) ? bk[l * 512 + r] : bq[l * 512 + r - 512];
}

// ---------------- unified MFMA GEMM, 2-phase prefetch ----------------
// A (M,K) AP planes (+z*sA); BT (N,K) BP planes, stride ldb, +z*sB.
// OM 0: row-major OP planes via f32-LDS coalesced epilogue.
// OM 1: f32 direct.
// OM 2: transpose-scatter (b,h,hs,n) planes (V).
// OM 3: KQ fused: n0<512 -> K row-major hi (coalesced path); else Q^T plane *0.125 -> Ch2.
template<int BM, int BN, int AP, int BP, int OM, int OP, bool ACT, bool BIAS, bool RES>
__global__ __launch_bounds__(256)
void gemm(const short* __restrict__ Ah, const short* __restrict__ Al,
          const short* __restrict__ BTh, const short* __restrict__ BTl,
          const float* __restrict__ bias,
          const short* __restrict__ ResH, const short* __restrict__ ResL,
          float* __restrict__ Cf, short* __restrict__ Ch, short* __restrict__ Cl,
          short* __restrict__ Ch2,
          int K, int ldb, int ldc, long sA, long sB, long sC)
{
  constexpr int MR = BM / 32, NR = BN / 32;
  constexpr int ABUF = BM * 32, BBUF = BN * 32;
  constexpr int STG = AP * ABUF + BP * BBUF;
  constexpr int TSZ2 = (OM == 2 || OM == 3) ? BN * (BM + 8) : 0;
  constexpr int TSZF = (OM == 0 || OM == 3) ? BM * (BN + 4) * 2 : 0;
  constexpr int SM1 = (2 * STG > TSZ2) ? 2 * STG : TSZ2;
  constexpr int SM = (SM1 > TSZF) ? SM1 : TSZF;
  __shared__ __align__(16) short smem[SM];

  const int z = blockIdx.z;
  const short* pAh = Ah + (long)z * sA;
  const short* pAl = Al + (long)z * sA;
  const short* pBh = BTh + (long)z * sB;
  const short* pBl = BTl + (long)z * sB;
  const int n0 = blockIdx.x * BN, m0 = blockIdx.y * BM;
  const int tid = threadIdx.x, lane = tid & 63, w = tid >> 6, g = lane >> 4, c = lane & 15;
  const int wm = w >> 1, wn = w & 1;

  auto stage = [&](int bb, int k0) {
    short* LA = smem + bb * STG;
    short* LB = LA + AP * ABUF;
#pragma unroll
    for (int p = 0; p < AP; ++p) {
      const short* src = p ? pAl : pAh;
#pragma unroll
      for (int t = 0; t < BM / 64; ++t) {
        int u = t * 256 + tid, gi = u / BM, row = u % BM;
        gload16(src + (long)(m0 + row) * K + k0 + gi * 8, LA + p * ABUF + u * 8);
      }
    }
#pragma unroll
    for (int p = 0; p < BP; ++p) {
      const short* src = p ? pBl : pBh;
#pragma unroll
      for (int t = 0; t < BN / 64; ++t) {
        int u = t * 256 + tid, gi = u / BN, col = u % BN;
        gload16(src + (long)(n0 + col) * ldb + k0 + gi * 8, LB + p * BBUF + u * 8);
      }
    }
  };

  f32x4 acc[MR][NR] = {};
  stage(0, 0);
  const int nk = K >> 5;
  for (int ks = 0; ks < nk; ++ks) {
    const int cur = ks & 1;
    __syncthreads();
    if (ks + 1 < nk) stage(cur ^ 1, (ks + 1) << 5);

    short* LA = smem + cur * STG;
    short* LB = LA + AP * ABUF;
    bf16x8 a_h[MR], a_l[MR], b_h[NR], b_l[NR];
#pragma unroll
    for (int i = 0; i < MR; ++i) {
      int idx = (g * BM + wm * (BM / 2) + i * 16 + c) * 8;
      a_h[i] = *(const bf16x8*)(LA + idx);
      if (AP == 2) a_l[i] = *(const bf16x8*)(LA + ABUF + idx);
    }
#pragma unroll
    for (int j = 0; j < NR; ++j) {
      int idx = (g * BN + wn * (BN / 2) + j * 16 + c) * 8;
      b_h[j] = *(const bf16x8*)(LB + idx);
      if (BP == 2) b_l[j] = *(const bf16x8*)(LB + BBUF + idx);
    }
    __builtin_amdgcn_s_setprio(1);
#pragma unroll
    for (int i = 0; i < MR; ++i)
#pragma unroll
      for (int j = 0; j < NR; ++j) {
        acc[i][j] = mfma16(a_h[i], b_h[j], acc[i][j]);
        if (BP == 2) acc[i][j] = mfma16(a_h[i], b_l[j], acc[i][j]);
        if (AP == 2) acc[i][j] = mfma16(a_l[i], b_h[j], acc[i][j]);
      }
    __builtin_amdgcn_s_setprio(0);
  }

  if constexpr (OM == 1) {
    // direct f32 stores (col = c across lanes -> 64B runs)
#pragma unroll
    for (int j = 0; j < NR; ++j) {
      int cl = wn * (BN / 2) + j * 16 + c;
      float bv = BIAS ? bias[n0 + cl] : 0.f;
#pragma unroll
      for (int i = 0; i < MR; ++i)
#pragma unroll
        for (int rr = 0; rr < 4; ++rr) {
          long row = m0 + wm * (BM / 2) + i * 16 + g * 4 + rr;
          float x = acc[i][j][rr] + bv;
          if (ACT) x = swishf(x);
          Cf[(long)z * sC + row * ldc + n0 + cl] = x;
        }
    }
    return;
  }

  if constexpr (OM == 0 || OM == 3) {
    if (OM == 0 || n0 < 512) {
      // coalesced row-major epilogue via f32 LDS transpose
      __syncthreads();
      float* Tf = (float*)smem;
      constexpr int LDT = BN + 4;
#pragma unroll
      for (int j = 0; j < NR; ++j) {
        int cl = wn * (BN / 2) + j * 16 + c;
        float bv = BIAS ? bias[n0 + cl] : 0.f;
#pragma unroll
        for (int i = 0; i < MR; ++i)
#pragma unroll
          for (int rr = 0; rr < 4; ++rr) {
            int rowl = wm * (BM / 2) + i * 16 + g * 4 + rr;
            float x = acc[i][j][rr] + bv;
            if (ACT) x = swishf(x);
            Tf[rowl * LDT + cl] = x;
          }
      }
      __syncthreads();
      constexpr int CH = BN / 8, NT = BM * CH / 256;
#pragma unroll
      for (int t = 0; t < NT; ++t) {
        int idx = t * 256 + tid, row = idx / CH, ch = idx % CH;
        long base = (long)z * sC + (long)(m0 + row) * ldc + (OM == 3 ? (n0 & 511) : n0) + ch * 8;
        float x8[8];
#pragma unroll
        for (int e = 0; e < 8; ++e) x8[e] = Tf[row * LDT + ch * 8 + e];
        if (RES) {
          bf16x8 rh = *(const bf16x8*)(ResH + base);
          bf16x8 rl8 = *(const bf16x8*)(ResL + base);
#pragma unroll
          for (int e = 0; e < 8; ++e) x8[e] += bf2f(rh[e]) + bf2f(rl8[e]);
        }
        short h8[8], l8[8];
#pragma unroll
        for (int e = 0; e < 8; ++e) split_bf(x8[e], h8[e], l8[e]);
        *(bf16x8*)(Ch + base) = *(const bf16x8*)&h8[0];
        if (OP == 2) *(bf16x8*)(Cl + base) = *(const bf16x8*)&l8[0];
      }
      return;
    }
  }

  if constexpr (OM == 2 || OM == 3) {
    // transpose-scatter -> (b,h,hs,n) planes
    short (*T)[BM + 8] = reinterpret_cast<short(*)[BM + 8]>(smem);
    const int h0 = (n0 & 511) >> 6;
    const int b = m0 >> 9, nn0 = m0 & 511;
    constexpr int NP = (OM == 3) ? 1 : OP;
#pragma unroll
    for (int p = 0; p < NP; ++p) {
      __syncthreads();
#pragma unroll
      for (int j = 0; j < NR; ++j) {
        int cl = wn * (BN / 2) + j * 16 + c;
        float bv = BIAS ? bias[n0 + cl] : 0.f;
#pragma unroll
        for (int i = 0; i < MR; ++i)
#pragma unroll
          for (int rr = 0; rr < 4; ++rr) {
            int rowl = wm * (BM / 2) + i * 16 + g * 4 + rr;
            float x = acc[i][j][rr] + bv;
            if (ACT) x = swishf(x);
            if (OM == 3) x *= 0.125f;          // fold 1/sqrt(hs) into Q
            short hi = f2bf(x);
            T[cl][rowl] = p ? f2bf(x - bf2f(hi)) : hi;
          }
      }
      __syncthreads();
      short* dp = (OM == 3) ? Ch2 : (p ? Cl : Ch);
      constexpr int RC = BM / 8;
#pragma unroll
      for (int q = 0; q < BN * BM / 2048; ++q) {
        int idx = q * 256 + tid, cl = idx / RC, r8 = (idx % RC) * 8;
        long ob = ((long)(b * 8 + h0 + (cl >> 6)) << 15) + (long)(cl & 63) * 512 + nn0 + r8;
        *(bf16x8*)(dp + ob) = *(const bf16x8*)&T[cl][r8];
      }
    }
  }
}

// ---------------- swapped-operand masked flash attention ----------------
// S^T = K @ U^T (per-lane P rows), per-lane online softmax, O^T = V^T @ P^T.
// O = (exp(s-m)/l)@V + OI;  OIT is dT@V transposed (hs,n), f32.
// grid: x = bh (XCD locality on K/V), y = i-tile.
__global__ __launch_bounds__(256)
void attn4(const short* __restrict__ Uh, const short* __restrict__ Kh,
           const short* __restrict__ VTh, const u64* __restrict__ bits,
           const float* __restrict__ OIT, short* __restrict__ Oh)
{
  __shared__ __align__(16) short LK[2][4096];   // K tile [d-grp][j][8]
  __shared__ __align__(16) short LV[2][4096];   // V^T tile [j-grp][hs][8]

  const int bh = blockIdx.x, b = bh >> 3, hd = bh & 7;
  const int i0 = blockIdx.y << 6;
  const int tid = threadIdx.x, lane = tid & 63, w = tid >> 6, g = lane >> 4, c = lane & 15;
  const int istrip = i0 + w * 16;
  const long plane = (long)bh << 15;

  auto stage = [&](int bb, int jt) {
#pragma unroll
    for (int t = 0; t < 2; ++t) {
      int u = t * 256 + tid, gi = u >> 6, j = u & 63;
      long ko = (long)(b * 512 + jt * 64 + j) * 512 + hd * 64 + gi * 8;
      gload16(Kh + ko, &LK[bb][0] + u * 8);
      long vo = plane + (long)j * 512 + jt * 64 + gi * 8;   // j slot = hs row
      gload16(VTh + vo, &LV[bb][0] + u * 8);
    }
  };

  stage(0, 0);

  bf16x8 uf[2];   // B-operand: U[i=istrip+c][d]  (U pre-scaled by 1/8)
#pragma unroll
  for (int ks = 0; ks < 2; ++ks)
    uf[ks] = *(const bf16x8*)(Uh + plane + (long)(istrip + c) * 64 + ks * 32 + g * 8);

  float m_run = NEG_INF, l_run = 0.f;
  f32x4 oeT[4] = {};
  const int srcA = (g & 1) * 32 + c, srcB = srcA + 16;
  const bool ghi = (g >> 1) != 0;

  for (int jt = 0; jt < 8; ++jt) {
    const int cur = jt & 1;
    __syncthreads();
    if (jt + 1 < 8) stage(cur ^ 1, jt + 1);

    // S^T[j][i]: lane (g,c) holds j = jt*64 + ct*16 + g*4 + rr for i = istrip+c
    f32x4 sacc[4] = {};
    __builtin_amdgcn_s_setprio(1);
#pragma unroll
    for (int ct = 0; ct < 4; ++ct)
#pragma unroll
      for (int ks = 0; ks < 2; ++ks) {
        bf16x8 kf = *(const bf16x8*)&LK[cur][((ks * 4 + g) * 64 + ct * 16 + c) * 8];
        sacc[ct] = mfma16(kf, uf[ks], sacc[ct]);
      }
    __builtin_amdgcn_s_setprio(0);

    const u64 wb = bits[(long)(istrip + c) * 8 + jt];

    // per-lane masked max (in-lane) + 2-step cross-g combine
    float vmax = NEG_INF;
#pragma unroll
    for (int ct = 0; ct < 4; ++ct)
#pragma unroll
      for (int rr = 0; rr < 4; ++rr)
        if ((wb >> (ct * 16 + g * 4 + rr)) & 1ull) vmax = fmaxf(vmax, sacc[ct][rr]);
    vmax = fmaxf(vmax, __shfl_xor(vmax, 16, 64));
    vmax = fmaxf(vmax, __shfl_xor(vmax, 32, 64));
    float mnew = fmaxf(m_run, vmax);
    float sf = (m_run > NEG_INF) ? __expf(m_run - mnew) : 0.f;

    float p[4][4], ps = 0.f;
#pragma unroll
    for (int ct = 0; ct < 4; ++ct)
#pragma unroll
      for (int rr = 0; rr < 4; ++rr) {
        bool bs = (wb >> (ct * 16 + g * 4 + rr)) & 1ull;
        float pe = bs ? __expf(sacc[ct][rr] - mnew) : 0.f;
        p[ct][rr] = pe; ps += pe;
      }
    ps += __shfl_xor(ps, 16, 64);
    ps += __shfl_xor(ps, 32, 64);
    l_run = l_run * sf + ps;
    m_run = mnew;
#pragma unroll
    for (int ht = 0; ht < 4; ++ht)
#pragma unroll
      for (int rr = 0; rr < 4; ++rr) oeT[ht][rr] *= sf;

    // pack P to bf16 pairs and redistribute into PV B-fragments
    unsigned q0[4], q1[4];
#pragma unroll
    for (int ct = 0; ct < 4; ++ct) {
      q0[ct] = cvtpk(p[ct][0], p[ct][1]);
      q1[ct] = cvtpk(p[ct][2], p[ct][3]);
    }
#pragma unroll
    for (int ksp = 0; ksp < 2; ++ksp) {
      unsigned a00 = __shfl(q0[2 * ksp], srcA, 64), a01 = __shfl(q0[2 * ksp + 1], srcA, 64);
      unsigned a10 = __shfl(q1[2 * ksp], srcA, 64), a11 = __shfl(q1[2 * ksp + 1], srcA, 64);
      unsigned b00 = __shfl(q0[2 * ksp], srcB, 64), b01 = __shfl(q0[2 * ksp + 1], srcB, 64);
      unsigned b10 = __shfl(q1[2 * ksp], srcB, 64), b11 = __shfl(q1[2 * ksp + 1], srcB, 64);
      union { unsigned u[4]; bf16x8 v; } pa;
      pa.u[0] = ghi ? a01 : a00;
      pa.u[1] = ghi ? a11 : a10;
      pa.u[2] = ghi ? b01 : b00;
      pa.u[3] = ghi ? b11 : b10;
      __builtin_amdgcn_s_setprio(1);
#pragma unroll
      for (int ht = 0; ht < 4; ++ht) {
        bf16x8 vf = *(const bf16x8*)&LV[cur][((ksp * 4 + g) * 64 + ht * 16 + c) * 8];
        oeT[ht] = mfma16(vf, pa.v, oeT[ht]);
      }
      __builtin_amdgcn_s_setprio(0);
    }
  }

  const float rl = (l_run > 0.f) ? 1.f / l_run : 0.f;

  // normalize, add OI^T, transpose via LDS, coalesced store
  __syncthreads();
  short* T = (short*)&LK[0][0];   // [64 i][72] bf16
#pragma unroll
  for (int ht = 0; ht < 4; ++ht)
#pragma unroll
    for (int rr = 0; rr < 4; ++rr) {
      int hs = ht * 16 + g * 4 + rr;
      float x = oeT[ht][rr] * rl + OIT[plane + (long)hs * 512 + i0 + w * 16 + c];
      T[(w * 16 + c) * 72 + hs] = f2bf(x);
    }
  __syncthreads();
#pragma unroll
  for (int t = 0; t < 2; ++t) {
    int idx = t * 256 + tid, row = idx >> 3, ch = idx & 7;
    *(bf16x8*)(Oh + (long)(b * 512 + i0 + row) * 512 + hd * 64 + ch * 8) =
        *(const bf16x8*)&T[row * 72 + ch * 8];
  }
}

// ---------------- host ----------------
extern "C" void kernel_launch(void* const* d_in, const int* in_sizes, int n_in,
                              void* d_out, int out_size, void* d_ws, size_t ws_size,
                              hipStream_t stream)
{
  const float* X   = (const float*)d_in[0];
  const int*   dag = (const int*)d_in[1];
  const float* Wk  = (const float*)d_in[2];
  const float* bk  = (const float*)d_in[3];
  const float* Wq  = (const float*)d_in[4];
  const float* bq  = (const float*)d_in[5];
  const float* Wv  = (const float*)d_in[6];
  const float* bv  = (const float*)d_in[7];
  const float* Wp  = (const float*)d_in[8];
  const float* bp  = (const float*)d_in[9];
  const float* W1  = (const float*)d_in[10];
  const float* b1  = (const float*)d_in[11];
  const float* W2  = (const float*)d_in[12];
  const float* b2  = (const float*)d_in[13];
  const float* Wlm = (const float*)d_in[14];
  const float* blm = (const float*)d_in[15];
  float* out = (float*)d_out;

  // ---- workspace (~73 MB) ----
  char* p = (char*)d_ws;
  auto alloc = [&](size_t n) { void* r = p; p += (n + 255) & ~(size_t)255; return r; };
  short* WkqTh = (short*)alloc(1048576 * 2);   // [l][1024][256] hi (K|Q)
  short* WvTh = (short*)alloc(524288 * 2);
  short* WpTh = (short*)alloc(524288 * 2);
  short* W1Th = (short*)alloc(1048576 * 2); short* W1Tl = (short*)alloc(1048576 * 2);
  short* W2Th = (short*)alloc(1048576 * 2); short* W2Tl = (short*)alloc(1048576 * 2);
  short* WlmTh = (short*)alloc(65536 * 2); short* WlmTl = (short*)alloc(65536 * 2);
  float* bkq = (float*)alloc(4096 * 4);
  short* dt0b = (short*)alloc(262144 * 2); short* dt1b = (short*)alloc(262144 * 2);
  u64* bits0 = (u64*)alloc(4096 * 8); u64* bits1 = (u64*)alloc(4096 * 8);
  short* Xh = (short*)alloc(2097152 * 2); short* Xl = (short*)alloc(2097152 * 2);
  short* Kh  = (short*)alloc(4194304 * 2);   // also mha hi+lo (2M+2M)
  short* QTh = (short*)alloc(4194304 * 2);   // Q^T; then O hi; ff1H spans QTh+VTh
  short* VTh = (short*)alloc(4194304 * 2);
  short* Uh  = (short*)alloc(4194304 * 2);   // U; ff1L spans Uh + OIT/2
  float* OIT = (float*)alloc(4194304 * 4);
  short* mhaH = Kh, *mhaL = Kh + 2097152;
  short* Oh = QTh;
  short* ff1H = QTh;   // 8192x1024 hi spans QTh..VTh
  short* ff1L = Uh;    // lo spans Uh..first half of OIT

  // ---- prep ----
  wsplit<1><<<dim3(1, 4, 32), 256, 0, stream>>>(Wk, WkqTh, nullptr, 256, 64, 8, 262144);
  wsplit<1><<<dim3(1, 4, 32), 256, 0, stream>>>(Wq, WkqTh + 131072, nullptr, 256, 64, 8, 262144);
  wsplit<1><<<dim3(1, 4, 32), 256, 0, stream>>>(Wv, WvTh, nullptr, 256, 64, 8, 131072);
  wsplit<1><<<dim3(4, 8, 4), 256, 0, stream>>>(Wp, WpTh, nullptr, 512, 256, 1, 131072);
  wsplit<2><<<dim3(16, 4, 4), 256, 0, stream>>>(W1, W1Th, W1Tl, 256, 1024, 1, 262144);
  wsplit<2><<<dim3(4, 16, 4), 256, 0, stream>>>(W2, W2Th, W2Tl, 1024, 256, 1, 262144);
  wsplit<2><<<dim3(4, 4, 1), 256, 0, stream>>>(Wlm, WlmTh, WlmTl, 256, 256, 1, 65536);
  prep_dt<<<512, 512, 0, stream>>>(dag, dt0b, dt1b, bits0, bits1);
  prep_x<<<8192, 256, 0, stream>>>(X, Xh, Xl);
  pack_kq<<<16, 256, 0, stream>>>(bk, bq, bkq);

  for (int l = 0; l < 4; ++l) {
    const short* dtb = l ? dt1b : dt0b;
    const u64* bts = l ? bits1 : bits0;
    // 1. KQ fused: K row-major hi; Q^T plane hi (x0.125)
    gemm<128, 64, 1, 1, 3, 1, true, true, false><<<dim3(16, 64), 256, 0, stream>>>(
        Xh, nullptr, WkqTh + l * 262144, nullptr, bkq + l * 1024, nullptr, nullptr,
        nullptr, Kh, nullptr, QTh, 256, 256, 512, 0, 0, 0);
    // 2. V -> V^T plane hi
    gemm<128, 64, 1, 1, 2, 1, true, true, false><<<dim3(8, 64), 256, 0, stream>>>(
        Xh, nullptr, WvTh + l * 131072, nullptr, bv + l * 512, nullptr, nullptr,
        nullptr, VTh, nullptr, nullptr, 256, 256, 0, 0, 0, 0);
    // 3. U = dT@Q (hi), batched over bh
    gemm<128, 64, 1, 1, 0, 1, false, false, false><<<dim3(1, 4, 128), 256, 0, stream>>>(
        dtb, nullptr, QTh, nullptr, nullptr, nullptr, nullptr,
        nullptr, Uh, nullptr, nullptr, 512, 512, 64, 0, 32768, 32768);
    // 4. OI^T = V^T @ dT^T (hi), f32 (bh, hs, n)
    gemm<64, 64, 1, 1, 1, 1, false, false, false><<<dim3(8, 1, 128), 256, 0, stream>>>(
        VTh, nullptr, dtb, nullptr, nullptr, nullptr, nullptr,
        OIT, nullptr, nullptr, nullptr, 512, 512, 512, 32768, 0, 32768);
    // 5. attention
    attn4<<<dim3(128, 8), 256, 0, stream>>>(Uh, Kh, VTh, bts, OIT, Oh);
    // 6. mha = swish(O@Wp+bp), hi/lo
    gemm<128, 64, 1, 1, 0, 2, true, true, false><<<dim3(4, 64), 256, 0, stream>>>(
        Oh, nullptr, WpTh + l * 131072, nullptr, bp + l * 256, nullptr, nullptr,
        nullptr, mhaH, mhaL, nullptr, 512, 512, 256, 0, 0, 0);
    // 7. ff1 = swish(mha@W1+b1), split
    gemm<128, 64, 2, 2, 0, 2, true, true, false><<<dim3(16, 64), 256, 0, stream>>>(
        mhaH, mhaL, W1Th + l * 262144, W1Tl + l * 262144, b1 + l * 1024, nullptr, nullptr,
        nullptr, ff1H, ff1L, nullptr, 256, 256, 1024, 0, 0, 0);
    // 8. X = mha + ff1@W2 + b2, split
    gemm<64, 64, 2, 2, 0, 2, false, true, true><<<dim3(4, 128), 256, 0, stream>>>(
        ff1H, ff1L, W2Th + l * 262144, W2Tl + l * 262144, b2 + l * 256, mhaH, mhaL,
        nullptr, Xh, Xl, nullptr, 1024, 1024, 256, 0, 0, 0);
  }
  // lm_head: out = X@Wlm + blm (f32)
  gemm<64, 64, 2, 2, 1, 1, false, true, false><<<dim3(4, 128), 256, 0, stream>>>(
      Xh, Xl, WlmTh, WlmTl, blm, nullptr, nullptr,
      out, nullptr, nullptr, nullptr, 256, 256, 256, 0, 0, 0);
}

// Round 7
// 794.041 us; speedup vs baseline: 32.0135x; 1.0007x over previous
//
#include <hip/hip_runtime.h>
#include <hip/hip_bf16.h>
#include <math.h>

// B=16, N=512, D=256, L=4, H=8, HS=64, FF=1024; M = B*N = 8192.
// Precision plan (exponential activation growth => only last-layer error matters):
//  - logit path (K, Q, U, QK^T, P): hi bf16
//  - V / dT@V / proj: hi bf16 (single-layer ~0.2-0.4% rel err, budget 2%)
//  - trunk (ff1, ff2, X, mha, lm): split-bf16  A@B ~= Ah@Bh + Ah@Bl + Al@Bh
// mfma_f32_16x16x32_bf16: A row=lane&15, k=(lane>>4)*8+e; B col=lane&15 same k;
// D col=lane&15, row=(lane>>4)*4+reg.

typedef __attribute__((ext_vector_type(8))) short bf16x8;
typedef __attribute__((ext_vector_type(4))) float f32x4;
typedef unsigned long long u64;

#define NEG_INF (-__builtin_inff())

__device__ __forceinline__ short f2bf(float x) {
  unsigned u = __float_as_uint(x);
  return (short)((u + 0x7FFFu + ((u >> 16) & 1u)) >> 16);
}
__device__ __forceinline__ float bf2f(short h) {
  return __uint_as_float(((unsigned)(unsigned short)h) << 16);
}
__device__ __forceinline__ void split_bf(float x, short& hi, short& lo) {
  hi = f2bf(x); lo = f2bf(x - bf2f(hi));
}
__device__ __forceinline__ float swishf(float x) { return x / (1.0f + __expf(-x)); }
__device__ __forceinline__ f32x4 mfma16(bf16x8 a, bf16x8 b, f32x4 c) {
  return __builtin_amdgcn_mfma_f32_16x16x32_bf16(a, b, c, 0, 0, 0);
}
__device__ __forceinline__ void gload16(const void* g, void* l) {
  __builtin_amdgcn_global_load_lds(
      (const __attribute__((address_space(1))) void*)g,
      (__attribute__((address_space(3))) void*)l, 16, 0, 0);
}
__device__ __forceinline__ unsigned cvtpk(float a, float b) {  // lo=bf16(a), hi=bf16(b)
  unsigned r;
  asm("v_cvt_pk_bf16_f32 %0, %1, %2" : "=v"(r) : "v"(a), "v"(b));
  return r;
}

// ---------------- weight transpose + split (P planes) ----------------
template<int P>
__global__ __launch_bounds__(256)
void wsplit(const float* __restrict__ in, short* __restrict__ oh, short* __restrict__ ol,
            int R, int C, int zh, long outLS)
{
  __shared__ float T[64][65];
  const int z = blockIdx.z;
  const long zin = (long)z * R * C;
  const long zout = (long)(z / zh) * outLS + (long)(z % zh) * R * C;
  const int r0 = blockIdx.y << 6, c0 = blockIdx.x << 6;
  const int lc = threadIdx.x & 63, p = threadIdx.x >> 6;
#pragma unroll
  for (int q = 0; q < 16; ++q) {
    int rr = p + q * 4;
    T[rr][lc] = in[zin + (long)(r0 + rr) * C + c0 + lc];
  }
  __syncthreads();
#pragma unroll
  for (int q = 0; q < 16; ++q) {
    int cr = p + q * 4;
    float x = T[lc][cr];
    long off = zout + (long)(c0 + cr) * R + r0 + lc;
    short hi = f2bf(x);
    oh[off] = hi;
    if (P == 2) ol[off] = f2bf(x - bf2f(hi));
  }
}

// ---------------- dag -> dT bf16 (hi) + bitmasks ----------------
__global__ __launch_bounds__(512)
void prep_dt(const int* __restrict__ dag, short* __restrict__ dt0, short* __restrict__ dt1,
             u64* __restrict__ bits0, u64* __restrict__ bits1)
{
  int i = blockIdx.x, j = threadIdx.x;
  bool v0 = dag[j * 512 + i] > 0;
  bool v1 = v0 || (i == j);
  const short one = (short)0x3F80;
  dt0[i * 512 + j] = v0 ? one : (short)0;
  dt1[i * 512 + j] = v1 ? one : (short)0;
  u64 b0 = __ballot(v0), b1 = __ballot(v1);
  if ((j & 63) == 0) { bits0[i * 8 + (j >> 6)] = b0; bits1[i * 8 + (j >> 6)] = b1; }
}

__global__ __launch_bounds__(256)
void prep_x(const float* __restrict__ X, short* __restrict__ Xh, short* __restrict__ Xl)
{
  int idx = blockIdx.x * 256 + threadIdx.x;
  short hi, lo; split_bf(X[idx], hi, lo);
  Xh[idx] = hi; Xl[idx] = lo;
}

__global__ __launch_bounds__(256)
void pack_kq(const float* __restrict__ bk, const float* __restrict__ bq,
             float* __restrict__ bkq)
{
  int t = blockIdx.x * 256 + threadIdx.x;
  if (t >= 4096) return;
  int l = t >> 10, r = t & 1023;
  bkq[t] = (r < 512) ? bk[l * 512 + r] : bq[l * 512 + r - 512];
}

// ---------------- unified MFMA GEMM, 2-phase prefetch ----------------
// A (M,K) AP planes (+z*sA); BT (N,K) BP planes, stride ldb, +z*sB.
// OM 0: row-major OP planes via f32-LDS coalesced epilogue.
// OM 1: f32 direct.
// OM 2: transpose-scatter (b,h,hs,n) planes (V).
// OM 3: KQ fused: n0<512 -> K row-major hi (coalesced path); else Q^T plane *0.125 -> Ch2.
template<int BM, int BN, int AP, int BP, int OM, int OP, bool ACT, bool BIAS, bool RES>
__global__ __launch_bounds__(256)
void gemm(const short* __restrict__ Ah, const short* __restrict__ Al,
          const short* __restrict__ BTh, const short* __restrict__ BTl,
          const float* __restrict__ bias,
          const short* __restrict__ ResH, const short* __restrict__ ResL,
          float* __restrict__ Cf, short* __restrict__ Ch, short* __restrict__ Cl,
          short* __restrict__ Ch2,
          int K, int ldb, int ldc, long sA, long sB, long sC)
{
  constexpr int MR = BM / 32, NR = BN / 32;
  constexpr int ABUF = BM * 32, BBUF = BN * 32;
  constexpr int STG = AP * ABUF + BP * BBUF;
  constexpr int TSZ2 = (OM == 2 || OM == 3) ? BN * (BM + 8) : 0;
  constexpr int TSZF = (OM == 0 || OM == 3) ? BM * (BN + 4) * 2 : 0;
  constexpr int SM1 = (2 * STG > TSZ2) ? 2 * STG : TSZ2;
  constexpr int SM = (SM1 > TSZF) ? SM1 : TSZF;
  __shared__ __align__(16) short smem[SM];

  const int z = blockIdx.z;
  const short* pAh = Ah + (long)z * sA;
  const short* pAl = Al + (long)z * sA;
  const short* pBh = BTh + (long)z * sB;
  const short* pBl = BTl + (long)z * sB;
  const int n0 = blockIdx.x * BN, m0 = blockIdx.y * BM;
  const int tid = threadIdx.x, lane = tid & 63, w = tid >> 6, g = lane >> 4, c = lane & 15;
  const int wm = w >> 1, wn = w & 1;

  auto stage = [&](int bb, int k0) {
    short* LA = smem + bb * STG;
    short* LB = LA + AP * ABUF;
#pragma unroll
    for (int p = 0; p < AP; ++p) {
      const short* src = p ? pAl : pAh;
#pragma unroll
      for (int t = 0; t < BM / 64; ++t) {
        int u = t * 256 + tid, gi = u / BM, row = u % BM;
        gload16(src + (long)(m0 + row) * K + k0 + gi * 8, LA + p * ABUF + u * 8);
      }
    }
#pragma unroll
    for (int p = 0; p < BP; ++p) {
      const short* src = p ? pBl : pBh;
#pragma unroll
      for (int t = 0; t < BN / 64; ++t) {
        int u = t * 256 + tid, gi = u / BN, col = u % BN;
        gload16(src + (long)(n0 + col) * ldb + k0 + gi * 8, LB + p * BBUF + u * 8);
      }
    }
  };

  f32x4 acc[MR][NR] = {};
  stage(0, 0);
  const int nk = K >> 5;
  for (int ks = 0; ks < nk; ++ks) {
    const int cur = ks & 1;
    __syncthreads();
    if (ks + 1 < nk) stage(cur ^ 1, (ks + 1) << 5);

    short* LA = smem + cur * STG;
    short* LB = LA + AP * ABUF;
    bf16x8 a_h[MR], a_l[MR], b_h[NR], b_l[NR];
#pragma unroll
    for (int i = 0; i < MR; ++i) {
      int idx = (g * BM + wm * (BM / 2) + i * 16 + c) * 8;
      a_h[i] = *(const bf16x8*)(LA + idx);
      if (AP == 2) a_l[i] = *(const bf16x8*)(LA + ABUF + idx);
    }
#pragma unroll
    for (int j = 0; j < NR; ++j) {
      int idx = (g * BN + wn * (BN / 2) + j * 16 + c) * 8;
      b_h[j] = *(const bf16x8*)(LB + idx);
      if (BP == 2) b_l[j] = *(const bf16x8*)(LB + BBUF + idx);
    }
    __builtin_amdgcn_s_setprio(1);
#pragma unroll
    for (int i = 0; i < MR; ++i)
#pragma unroll
      for (int j = 0; j < NR; ++j) {
        acc[i][j] = mfma16(a_h[i], b_h[j], acc[i][j]);
        if (BP == 2) acc[i][j] = mfma16(a_h[i], b_l[j], acc[i][j]);
        if (AP == 2) acc[i][j] = mfma16(a_l[i], b_h[j], acc[i][j]);
      }
    __builtin_amdgcn_s_setprio(0);
  }

  if constexpr (OM == 1) {
    // direct f32 stores (col = c across lanes -> 64B runs)
#pragma unroll
    for (int j = 0; j < NR; ++j) {
      int cl = wn * (BN / 2) + j * 16 + c;
      float bv = BIAS ? bias[n0 + cl] : 0.f;
#pragma unroll
      for (int i = 0; i < MR; ++i)
#pragma unroll
        for (int rr = 0; rr < 4; ++rr) {
          long row = m0 + wm * (BM / 2) + i * 16 + g * 4 + rr;
          float x = acc[i][j][rr] + bv;
          if (ACT) x = swishf(x);
          Cf[(long)z * sC + row * ldc + n0 + cl] = x;
        }
    }
    return;
  }

  if constexpr (OM == 0 || OM == 3) {
    if (OM == 0 || n0 < 512) {
      // coalesced row-major epilogue via f32 LDS transpose
      __syncthreads();
      float* Tf = (float*)smem;
      constexpr int LDT = BN + 4;
#pragma unroll
      for (int j = 0; j < NR; ++j) {
        int cl = wn * (BN / 2) + j * 16 + c;
        float bv = BIAS ? bias[n0 + cl] : 0.f;
#pragma unroll
        for (int i = 0; i < MR; ++i)
#pragma unroll
          for (int rr = 0; rr < 4; ++rr) {
            int rowl = wm * (BM / 2) + i * 16 + g * 4 + rr;
            float x = acc[i][j][rr] + bv;
            if (ACT) x = swishf(x);
            Tf[rowl * LDT + cl] = x;
          }
      }
      __syncthreads();
      constexpr int CH = BN / 8, NT = BM * CH / 256;
#pragma unroll
      for (int t = 0; t < NT; ++t) {
        int idx = t * 256 + tid, row = idx / CH, ch = idx % CH;
        long base = (long)z * sC + (long)(m0 + row) * ldc + (OM == 3 ? (n0 & 511) : n0) + ch * 8;
        float x8[8];
#pragma unroll
        for (int e = 0; e < 8; ++e) x8[e] = Tf[row * LDT + ch * 8 + e];
        if (RES) {
          bf16x8 rh = *(const bf16x8*)(ResH + base);
          bf16x8 rl8 = *(const bf16x8*)(ResL + base);
#pragma unroll
          for (int e = 0; e < 8; ++e) x8[e] += bf2f(rh[e]) + bf2f(rl8[e]);
        }
        short h8[8], l8[8];
#pragma unroll
        for (int e = 0; e < 8; ++e) split_bf(x8[e], h8[e], l8[e]);
        *(bf16x8*)(Ch + base) = *(const bf16x8*)&h8[0];
        if (OP == 2) *(bf16x8*)(Cl + base) = *(const bf16x8*)&l8[0];
      }
      return;
    }
  }

  if constexpr (OM == 2 || OM == 3) {
    // transpose-scatter -> (b,h,hs,n) planes
    short (*T)[BM + 8] = reinterpret_cast<short(*)[BM + 8]>(smem);
    const int h0 = (n0 & 511) >> 6;
    const int b = m0 >> 9, nn0 = m0 & 511;
    constexpr int NP = (OM == 3) ? 1 : OP;
#pragma unroll
    for (int p = 0; p < NP; ++p) {
      __syncthreads();
#pragma unroll
      for (int j = 0; j < NR; ++j) {
        int cl = wn * (BN / 2) + j * 16 + c;
        float bv = BIAS ? bias[n0 + cl] : 0.f;
#pragma unroll
        for (int i = 0; i < MR; ++i)
#pragma unroll
          for (int rr = 0; rr < 4; ++rr) {
            int rowl = wm * (BM / 2) + i * 16 + g * 4 + rr;
            float x = acc[i][j][rr] + bv;
            if (ACT) x = swishf(x);
            if (OM == 3) x *= 0.125f;          // fold 1/sqrt(hs) into Q
            short hi = f2bf(x);
            T[cl][rowl] = p ? f2bf(x - bf2f(hi)) : hi;
          }
      }
      __syncthreads();
      short* dp = (OM == 3) ? Ch2 : (p ? Cl : Ch);
      constexpr int RC = BM / 8;
#pragma unroll
      for (int q = 0; q < BN * BM / 2048; ++q) {
        int idx = q * 256 + tid, cl = idx / RC, r8 = (idx % RC) * 8;
        long ob = ((long)(b * 8 + h0 + (cl >> 6)) << 15) + (long)(cl & 63) * 512 + nn0 + r8;
        *(bf16x8*)(dp + ob) = *(const bf16x8*)&T[cl][r8];
      }
    }
  }
}

// ---------------- swapped-operand masked flash attention ----------------
// S^T = K @ U^T (per-lane P rows), per-lane online softmax, O^T = V^T @ P^T.
// O = (exp(s-m)/l)@V + OI;  OIT is dT@V transposed (hs,n), f32.
// grid: x = bh (XCD locality on K/V), y = i-tile.
__global__ __launch_bounds__(256)
void attn4(const short* __restrict__ Uh, const short* __restrict__ Kh,
           const short* __restrict__ VTh, const u64* __restrict__ bits,
           const float* __restrict__ OIT, short* __restrict__ Oh)
{
  __shared__ __align__(16) short LK[2][4096];   // K tile [d-grp][j][8]
  __shared__ __align__(16) short LV[2][4096];   // V^T tile [j-grp][hs][8]

  const int bh = blockIdx.x, b = bh >> 3, hd = bh & 7;
  const int i0 = blockIdx.y << 6;
  const int tid = threadIdx.x, lane = tid & 63, w = tid >> 6, g = lane >> 4, c = lane & 15;
  const int istrip = i0 + w * 16;
  const long plane = (long)bh << 15;

  auto stage = [&](int bb, int jt) {
#pragma unroll
    for (int t = 0; t < 2; ++t) {
      int u = t * 256 + tid, gi = u >> 6, j = u & 63;
      long ko = (long)(b * 512 + jt * 64 + j) * 512 + hd * 64 + gi * 8;
      gload16(Kh + ko, &LK[bb][0] + u * 8);
      long vo = plane + (long)j * 512 + jt * 64 + gi * 8;   // j slot = hs row
      gload16(VTh + vo, &LV[bb][0] + u * 8);
    }
  };

  stage(0, 0);

  bf16x8 uf[2];   // B-operand: U[i=istrip+c][d]  (U pre-scaled by 1/8)
#pragma unroll
  for (int ks = 0; ks < 2; ++ks)
    uf[ks] = *(const bf16x8*)(Uh + plane + (long)(istrip + c) * 64 + ks * 32 + g * 8);

  float m_run = NEG_INF, l_run = 0.f;
  f32x4 oeT[4] = {};
  const int srcA = (g & 1) * 32 + c, srcB = srcA + 16;
  const bool ghi = (g >> 1) != 0;

  for (int jt = 0; jt < 8; ++jt) {
    const int cur = jt & 1;
    __syncthreads();
    if (jt + 1 < 8) stage(cur ^ 1, jt + 1);

    // S^T[j][i]: lane (g,c) holds j = jt*64 + ct*16 + g*4 + rr for i = istrip+c
    f32x4 sacc[4] = {};
    __builtin_amdgcn_s_setprio(1);
#pragma unroll
    for (int ct = 0; ct < 4; ++ct)
#pragma unroll
      for (int ks = 0; ks < 2; ++ks) {
        bf16x8 kf = *(const bf16x8*)&LK[cur][((ks * 4 + g) * 64 + ct * 16 + c) * 8];
        sacc[ct] = mfma16(kf, uf[ks], sacc[ct]);
      }
    __builtin_amdgcn_s_setprio(0);

    const u64 wb = bits[(long)(istrip + c) * 8 + jt];

    // per-lane masked max (in-lane) + 2-step cross-g combine
    float vmax = NEG_INF;
#pragma unroll
    for (int ct = 0; ct < 4; ++ct)
#pragma unroll
      for (int rr = 0; rr < 4; ++rr)
        if ((wb >> (ct * 16 + g * 4 + rr)) & 1ull) vmax = fmaxf(vmax, sacc[ct][rr]);
    vmax = fmaxf(vmax, __shfl_xor(vmax, 16, 64));
    vmax = fmaxf(vmax, __shfl_xor(vmax, 32, 64));
    float mnew = fmaxf(m_run, vmax);
    float sf = (m_run > NEG_INF) ? __expf(m_run - mnew) : 0.f;

    float p[4][4], ps = 0.f;
#pragma unroll
    for (int ct = 0; ct < 4; ++ct)
#pragma unroll
      for (int rr = 0; rr < 4; ++rr) {
        bool bs = (wb >> (ct * 16 + g * 4 + rr)) & 1ull;
        float pe = bs ? __expf(sacc[ct][rr] - mnew) : 0.f;
        p[ct][rr] = pe; ps += pe;
      }
    ps += __shfl_xor(ps, 16, 64);
    ps += __shfl_xor(ps, 32, 64);
    l_run = l_run * sf + ps;
    m_run = mnew;
#pragma unroll
    for (int ht = 0; ht < 4; ++ht)
#pragma unroll
      for (int rr = 0; rr < 4; ++rr) oeT[ht][rr] *= sf;

    // pack P to bf16 pairs and redistribute into PV B-fragments
    unsigned q0[4], q1[4];
#pragma unroll
    for (int ct = 0; ct < 4; ++ct) {
      q0[ct] = cvtpk(p[ct][0], p[ct][1]);
      q1[ct] = cvtpk(p[ct][2], p[ct][3]);
    }
#pragma unroll
    for (int ksp = 0; ksp < 2; ++ksp) {
      unsigned a00 = __shfl(q0[2 * ksp], srcA, 64), a01 = __shfl(q0[2 * ksp + 1], srcA, 64);
      unsigned a10 = __shfl(q1[2 * ksp], srcA, 64), a11 = __shfl(q1[2 * ksp + 1], srcA, 64);
      unsigned b00 = __shfl(q0[2 * ksp], srcB, 64), b01 = __shfl(q0[2 * ksp + 1], srcB, 64);
      unsigned b10 = __shfl(q1[2 * ksp], srcB, 64), b11 = __shfl(q1[2 * ksp + 1], srcB, 64);
      union { unsigned u[4]; bf16x8 v; } pa;
      pa.u[0] = ghi ? a01 : a00;
      pa.u[1] = ghi ? a11 : a10;
      pa.u[2] = ghi ? b01 : b00;
      pa.u[3] = ghi ? b11 : b10;
      __builtin_amdgcn_s_setprio(1);
#pragma unroll
      for (int ht = 0; ht < 4; ++ht) {
        bf16x8 vf = *(const bf16x8*)&LV[cur][((ksp * 4 + g) * 64 + ht * 16 + c) * 8];
        oeT[ht] = mfma16(vf, pa.v, oeT[ht]);
      }
      __builtin_amdgcn_s_setprio(0);
    }
  }

  const float rl = (l_run > 0.f) ? 1.f / l_run : 0.f;

  // normalize, add OI^T, transpose via LDS, coalesced store
  __syncthreads();
  short* T = (short*)&LK[0][0];   // [64 i][72] bf16
#pragma unroll
  for (int ht = 0; ht < 4; ++ht)
#pragma unroll
    for (int rr = 0; rr < 4; ++rr) {
      int hs = ht * 16 + g * 4 + rr;
      float x = oeT[ht][rr] * rl + OIT[plane + (long)hs * 512 + i0 + w * 16 + c];
      T[(w * 16 + c) * 72 + hs] = f2bf(x);
    }
  __syncthreads();
#pragma unroll
  for (int t = 0; t < 2; ++t) {
    int idx = t * 256 + tid, row = idx >> 3, ch = idx & 7;
    *(bf16x8*)(Oh + (long)(b * 512 + i0 + row) * 512 + hd * 64 + ch * 8) =
        *(const bf16x8*)&T[row * 72 + ch * 8];
  }
}

// ---------------- host ----------------
extern "C" void kernel_launch(void* const* d_in, const int* in_sizes, int n_in,
                              void* d_out, int out_size, void* d_ws, size_t ws_size,
                              hipStream_t stream)
{
  const float* X   = (const float*)d_in[0];
  const int*   dag = (const int*)d_in[1];
  const float* Wk  = (const float*)d_in[2];
  const float* bk  = (const float*)d_in[3];
  const float* Wq  = (const float*)d_in[4];
  const float* bq  = (const float*)d_in[5];
  const float* Wv  = (const float*)d_in[6];
  const float* bv  = (const float*)d_in[7];
  const float* Wp  = (const float*)d_in[8];
  const float* bp  = (const float*)d_in[9];
  const float* W1  = (const float*)d_in[10];
  const float* b1  = (const float*)d_in[11];
  const float* W2  = (const float*)d_in[12];
  const float* b2  = (const float*)d_in[13];
  const float* Wlm = (const float*)d_in[14];
  const float* blm = (const float*)d_in[15];
  float* out = (float*)d_out;

  // ---- workspace (~73 MB) ----
  char* p = (char*)d_ws;
  auto alloc = [&](size_t n) { void* r = p; p += (n + 255) & ~(size_t)255; return r; };
  short* WkqTh = (short*)alloc(1048576 * 2);   // [l][1024][256] hi (K|Q)
  short* WvTh = (short*)alloc(524288 * 2);
  short* WpTh = (short*)alloc(524288 * 2);
  short* W1Th = (short*)alloc(1048576 * 2); short* W1Tl = (short*)alloc(1048576 * 2);
  short* W2Th = (short*)alloc(1048576 * 2); short* W2Tl = (short*)alloc(1048576 * 2);
  short* WlmTh = (short*)alloc(65536 * 2); short* WlmTl = (short*)alloc(65536 * 2);
  float* bkq = (float*)alloc(4096 * 4);
  short* dt0b = (short*)alloc(262144 * 2); short* dt1b = (short*)alloc(262144 * 2);
  u64* bits0 = (u64*)alloc(4096 * 8); u64* bits1 = (u64*)alloc(4096 * 8);
  short* Xh = (short*)alloc(2097152 * 2); short* Xl = (short*)alloc(2097152 * 2);
  short* Kh  = (short*)alloc(4194304 * 2);   // also mha hi+lo (2M+2M)
  short* QTh = (short*)alloc(4194304 * 2);   // Q^T; then O hi; ff1H spans QTh+VTh
  short* VTh = (short*)alloc(4194304 * 2);
  short* Uh  = (short*)alloc(4194304 * 2);   // U; ff1L spans Uh + OIT/2
  float* OIT = (float*)alloc(4194304 * 4);
  short* mhaH = Kh, *mhaL = Kh + 2097152;
  short* Oh = QTh;
  short* ff1H = QTh;   // 8192x1024 hi spans QTh..VTh
  short* ff1L = Uh;    // lo spans Uh..first half of OIT

  // ---- prep ----
  wsplit<1><<<dim3(1, 4, 32), 256, 0, stream>>>(Wk, WkqTh, nullptr, 256, 64, 8, 262144);
  wsplit<1><<<dim3(1, 4, 32), 256, 0, stream>>>(Wq, WkqTh + 131072, nullptr, 256, 64, 8, 262144);
  wsplit<1><<<dim3(1, 4, 32), 256, 0, stream>>>(Wv, WvTh, nullptr, 256, 64, 8, 131072);
  wsplit<1><<<dim3(4, 8, 4), 256, 0, stream>>>(Wp, WpTh, nullptr, 512, 256, 1, 131072);
  wsplit<2><<<dim3(16, 4, 4), 256, 0, stream>>>(W1, W1Th, W1Tl, 256, 1024, 1, 262144);
  wsplit<2><<<dim3(4, 16, 4), 256, 0, stream>>>(W2, W2Th, W2Tl, 1024, 256, 1, 262144);
  wsplit<2><<<dim3(4, 4, 1), 256, 0, stream>>>(Wlm, WlmTh, WlmTl, 256, 256, 1, 65536);
  prep_dt<<<512, 512, 0, stream>>>(dag, dt0b, dt1b, bits0, bits1);
  prep_x<<<8192, 256, 0, stream>>>(X, Xh, Xl);
  pack_kq<<<16, 256, 0, stream>>>(bk, bq, bkq);

  for (int l = 0; l < 4; ++l) {
    const short* dtb = l ? dt1b : dt0b;
    const u64* bts = l ? bits1 : bits0;
    // 1. KQ fused: K row-major hi; Q^T plane hi (x0.125)
    gemm<128, 64, 1, 1, 3, 1, true, true, false><<<dim3(16, 64), 256, 0, stream>>>(
        Xh, nullptr, WkqTh + l * 262144, nullptr, bkq + l * 1024, nullptr, nullptr,
        nullptr, Kh, nullptr, QTh, 256, 256, 512, 0, 0, 0);
    // 2. V -> V^T plane hi
    gemm<128, 64, 1, 1, 2, 1, true, true, false><<<dim3(8, 64), 256, 0, stream>>>(
        Xh, nullptr, WvTh + l * 131072, nullptr, bv + l * 512, nullptr, nullptr,
        nullptr, VTh, nullptr, nullptr, 256, 256, 0, 0, 0, 0);
    // 3. U = dT@Q (hi), batched over bh
    gemm<128, 64, 1, 1, 0, 1, false, false, false><<<dim3(1, 4, 128), 256, 0, stream>>>(
        dtb, nullptr, QTh, nullptr, nullptr, nullptr, nullptr,
        nullptr, Uh, nullptr, nullptr, 512, 512, 64, 0, 32768, 32768);
    // 4. OI^T = V^T @ dT^T (hi), f32 (bh, hs, n)
    gemm<64, 64, 1, 1, 1, 1, false, false, false><<<dim3(8, 1, 128), 256, 0, stream>>>(
        VTh, nullptr, dtb, nullptr, nullptr, nullptr, nullptr,
        OIT, nullptr, nullptr, nullptr, 512, 512, 512, 32768, 0, 32768);
    // 5. attention
    attn4<<<dim3(128, 8), 256, 0, stream>>>(Uh, Kh, VTh, bts, OIT, Oh);
    // 6. mha = swish(O@Wp+bp), hi/lo
    gemm<128, 64, 1, 1, 0, 2, true, true, false><<<dim3(4, 64), 256, 0, stream>>>(
        Oh, nullptr, WpTh + l * 131072, nullptr, bp + l * 256, nullptr, nullptr,
        nullptr, mhaH, mhaL, nullptr, 512, 512, 256, 0, 0, 0);
    // 7. ff1 = swish(mha@W1+b1), split
    gemm<128, 64, 2, 2, 0, 2, true, true, false><<<dim3(16, 64), 256, 0, stream>>>(
        mhaH, mhaL, W1Th + l * 262144, W1Tl + l * 262144, b1 + l * 1024, nullptr, nullptr,
        nullptr, ff1H, ff1L, nullptr, 256, 256, 1024, 0, 0, 0);
    // 8. X = mha + ff1@W2 + b2, split
    gemm<64, 64, 2, 2, 0, 2, false, true, true><<<dim3(4, 128), 256, 0, stream>>>(
        ff1H, ff1L, W2Th + l * 262144, W2Tl + l * 262144, b2 + l * 256, mhaH, mhaL,
        nullptr, Xh, Xl, nullptr, 1024, 1024, 256, 0, 0, 0);
  }
  // lm_head: out = X@Wlm + blm (f32)
  gemm<64, 64, 2, 2, 1, 1, false, true, false><<<dim3(4, 128), 256, 0, stream>>>(
      Xh, Xl, WlmTh, WlmTl, blm, nullptr, nullptr,
      out, nullptr, nullptr, nullptr, 256, 256, 256, 0, 0, 0);
}